// Round 4
// baseline (2301.583 us; speedup 1.0000x reference)
//
#include <hip/hip_runtime.h>
#include <hip/hip_bf16.h>
#include <cstdint>
#include <cstddef>

using bf16 = __hip_bfloat16;
typedef __attribute__((ext_vector_type(4))) float f32x4;
typedef __attribute__((ext_vector_type(8))) short bf16x8;

#define B_ 128
#define L_ 196
#define T_ 25
#define V_ 10000
#define NBLK 256

__device__ __forceinline__ float b2f(short s) {
  unsigned u = ((unsigned)(unsigned short)s) << 16;
  return __uint_as_float(u);
}
__device__ __forceinline__ bf16 f2b(float f) { return __float2bfloat16(f); }
__device__ __forceinline__ short f2bs(float f) {
  return __builtin_bit_cast(short, __float2bfloat16(f));
}
__device__ __forceinline__ float sigf(float x) { return 1.f / (1.f + __expf(-x)); }
__device__ __forceinline__ float tanh_fast(float x) { return 1.f - 2.f / (1.f + __expf(2.f * x)); }

// Fragment-packed layout: 16x32 tiles, tile-row-major; element (r,c) at
// (((r>>4)*KT + (c>>5))*64 + ((c&31)>>3)*16 + (r&15))*8 + (c&7).
// A wave's MFMA fragment is base + lane*8 elems = one contiguous 1KiB load.
__device__ __forceinline__ size_t pidx(int row, int col, int K) {
  int KT = K >> 5;
  return (((size_t)(row >> 4) * KT + (col >> 5)) * 64 +
          (size_t)(((col & 31) >> 3) * 16 + (row & 15))) * 8 + (col & 7);
}

__device__ __forceinline__ float wred_sum(float x) {
#pragma unroll
  for (int off = 32; off >= 1; off >>= 1) x += __shfl_xor(x, off, 64);
  return x;
}
__device__ __forceinline__ float wred_max(float x) {
#pragma unroll
  for (int off = 32; off >= 1; off >>= 1) x = fmaxf(x, __shfl_xor(x, off, 64));
  return x;
}

// ---- two-level grid barrier (16 groups x 16 blocks), monotone counters ----
__device__ __forceinline__ void gbar(unsigned* bs) {
  __syncthreads();
  if (threadIdx.x == 0) {
    unsigned* lcnt = bs;            // 16 shards at stride 32 (128B apart)
    unsigned* cnt  = bs + 512;
    unsigned* gen  = bs + 544;
    unsigned g = __hip_atomic_load(gen, __ATOMIC_RELAXED, __HIP_MEMORY_SCOPE_AGENT);
    int grp = (int)(blockIdx.x & 15u);
    unsigned a = __hip_atomic_fetch_add(&lcnt[grp * 32], 1u, __ATOMIC_ACQ_REL,
                                        __HIP_MEMORY_SCOPE_AGENT);
    bool done = false;
    if ((a & 15u) == 15u) {
      unsigned b = __hip_atomic_fetch_add(cnt, 1u, __ATOMIC_ACQ_REL,
                                          __HIP_MEMORY_SCOPE_AGENT);
      if ((b & 15u) == 15u) {
        __hip_atomic_store(gen, g + 1u, __ATOMIC_RELEASE, __HIP_MEMORY_SCOPE_AGENT);
        done = true;
      }
    }
    if (!done) {
      while (__hip_atomic_load(gen, __ATOMIC_RELAXED, __HIP_MEMORY_SCOPE_AGENT) == g)
        __builtin_amdgcn_s_sleep(1);
    }
    __threadfence();
  }
  __syncthreads();
}

// ---- persistent scan kernel: 25 steps, 2 grid barriers per step ----
__global__ __launch_bounds__(256, 2) void scan_fused(
    bf16* __restrict__ A1,          // (T_+1) slots x (128x1024 packed): [x | h]
    const bf16* __restrict__ WT_g,  // 2560x1024 packed
    const float* __restrict__ bgx,  // 2560 combined bias
    float* __restrict__ cbuf,       // 128x512 f32 cell state
    float* __restrict__ sbuf,       // 2 x 128x512 f32 (ping-pong)
    bf16* __restrict__ Aag,         // 128x1024 packed [h|s]
    bf16* __restrict__ projA,       // T_ slots x (128x1024 packed): [h | ctx]
    const bf16* __restrict__ WT_a,  // 1024x1024 packed
    const float* __restrict__ bax,  // 1024 combined bias
    float* __restrict__ agswb,      // 128x1024 f32
    const bf16* __restrict__ attv,  // 25088x512 row-major bf16
    const float* __restrict__ w_a,  // 512
    const bf16* __restrict__ enc_p, // 25088x512 packed bf16
    const int* __restrict__ clen,
    float* __restrict__ alphas, float* __restrict__ betas,
    unsigned* __restrict__ bar)
{
  const int blk = blockIdx.x;
  const int tid = threadIdx.x;
  const int wv = tid >> 6, lane = tid & 63;
  const int r16 = lane & 15, kg = lane >> 4;
  __shared__ float sh[200];
  __shared__ float red[8];

  for (int tt = 0; tt <= T_; ++tt) {
    if (blk >= 128) {
      // ---- P1: gates GEMM (t=tt) + fused LSTM pointwise, one wave per block
      if (tt < T_ && wv == 0) {
        int job = blk - 128;            // 0..127
        int mi = job >> 5;              // 0..3: 32-row tile
        int di = job & 31;              // 0..31: 16-col d tile
        const bf16* A1t = A1 + (size_t)tt * 131072;
        f32x4 acc[2][5];
#pragma unroll
        for (int i = 0; i < 2; i++)
#pragma unroll
          for (int g = 0; g < 5; g++) acc[i][g] = f32x4{0.f, 0.f, 0.f, 0.f};
        const bf16* ap0 = A1t + ((size_t)(mi * 2 + 0) * 32) * 512 + lane * 8;
        const bf16* ap1 = A1t + ((size_t)(mi * 2 + 1) * 32) * 512 + lane * 8;
        const bf16* bp0 = WT_g + ((size_t)(0 * 32 + di) * 32) * 512 + lane * 8;
        const bf16* bp1 = WT_g + ((size_t)(1 * 32 + di) * 32) * 512 + lane * 8;
        const bf16* bp2 = WT_g + ((size_t)(2 * 32 + di) * 32) * 512 + lane * 8;
        const bf16* bp3 = WT_g + ((size_t)(3 * 32 + di) * 32) * 512 + lane * 8;
        const bf16* bp4 = WT_g + ((size_t)(4 * 32 + di) * 32) * 512 + lane * 8;
#pragma unroll 2
        for (int kt = 0; kt < 32; kt++) {
          bf16x8 a0 = *(const bf16x8*)(const void*)(ap0 + (size_t)kt * 512);
          bf16x8 a1 = *(const bf16x8*)(const void*)(ap1 + (size_t)kt * 512);
          bf16x8 b0 = *(const bf16x8*)(const void*)(bp0 + (size_t)kt * 512);
          bf16x8 b1 = *(const bf16x8*)(const void*)(bp1 + (size_t)kt * 512);
          bf16x8 b2 = *(const bf16x8*)(const void*)(bp2 + (size_t)kt * 512);
          bf16x8 b3 = *(const bf16x8*)(const void*)(bp3 + (size_t)kt * 512);
          bf16x8 b4 = *(const bf16x8*)(const void*)(bp4 + (size_t)kt * 512);
          acc[0][0] = __builtin_amdgcn_mfma_f32_16x16x32_bf16(a0, b0, acc[0][0], 0, 0, 0);
          acc[1][0] = __builtin_amdgcn_mfma_f32_16x16x32_bf16(a1, b0, acc[1][0], 0, 0, 0);
          acc[0][1] = __builtin_amdgcn_mfma_f32_16x16x32_bf16(a0, b1, acc[0][1], 0, 0, 0);
          acc[1][1] = __builtin_amdgcn_mfma_f32_16x16x32_bf16(a1, b1, acc[1][1], 0, 0, 0);
          acc[0][2] = __builtin_amdgcn_mfma_f32_16x16x32_bf16(a0, b2, acc[0][2], 0, 0, 0);
          acc[1][2] = __builtin_amdgcn_mfma_f32_16x16x32_bf16(a1, b2, acc[1][2], 0, 0, 0);
          acc[0][3] = __builtin_amdgcn_mfma_f32_16x16x32_bf16(a0, b3, acc[0][3], 0, 0, 0);
          acc[1][3] = __builtin_amdgcn_mfma_f32_16x16x32_bf16(a1, b3, acc[1][3], 0, 0, 0);
          acc[0][4] = __builtin_amdgcn_mfma_f32_16x16x32_bf16(a0, b4, acc[0][4], 0, 0, 0);
          acc[1][4] = __builtin_amdgcn_mfma_f32_16x16x32_bf16(a1, b4, acc[1][4], 0, 0, 0);
        }
        int d = di * 16 + r16;
        float bi0 = bgx[d], bi1 = bgx[512 + d], bi2 = bgx[1024 + d];
        float bi3 = bgx[1536 + d], bi4 = bgx[2048 + d];
        bf16* hnext = A1 + (size_t)(tt + 1) * 131072;
        bf16* pA = projA + (size_t)tt * 131072;
        float* sb = sbuf + (size_t)(tt & 1) * 65536;
#pragma unroll
        for (int i = 0; i < 2; i++)
#pragma unroll
          for (int r = 0; r < 4; r++) {
            int m = mi * 32 + i * 16 + kg * 4 + r;
            float gi_ = acc[i][0][r] + bi0;
            float gf_ = acc[i][1][r] + bi1;
            float gg_ = acc[i][2][r] + bi2;
            float go_ = acc[i][3][r] + bi3;
            float gx_ = acc[i][4][r] + bi4;
            float co = cbuf[m * 512 + d];
            float cn = sigf(gf_) * co + sigf(gi_) * tanh_fast(gg_);
            float tcn = tanh_fast(cn);
            float hn = sigf(go_) * tcn;
            float ss = sigf(gx_) * tcn;
            cbuf[m * 512 + d] = cn;
            sb[m * 512 + d] = ss;
            bf16 hb = f2b(hn), sv = f2b(ss);
            size_t plo = pidx(m, d, 1024), phi = pidx(m, 512 + d, 1024);
            Aag[plo] = hb;
            Aag[phi] = sv;
            pA[plo] = hb;
            hnext[phi] = hb;
          }
      }
    } else {
      // ---- P4: attention for t = tt-1, one block per batch element
      if (tt >= 1) {
        int t = tt - 1, b = blk;
        const float* ag = agswb + b * 1024;
        int a0 = lane * 8;
        float ag8[8], wa8[8];
#pragma unroll
        for (int j = 0; j < 8; j++) { ag8[j] = ag[a0 + j]; wa8[j] = w_a[a0 + j]; }
        for (int l = wv; l < 197; l += 4) {
          float part = 0.f;
          if (l < 196) {
            bf16x8 av = *(const bf16x8*)(const void*)(attv + ((size_t)(b * 196 + l)) * 512 + a0);
#pragma unroll
            for (int j = 0; j < 8; j++) part += wa8[j] * tanh_fast(b2f(av[j]) + ag8[j]);
          } else {
#pragma unroll
            for (int j = 0; j < 8; j++) part += wa8[j] * tanh_fast(ag[512 + a0 + j] + ag8[j]);
          }
          part = wred_sum(part);
          if (lane == 0) sh[l] = part;
        }
        __syncthreads();
        float v = (tid < 197) ? sh[tid] : -1e30f;
        float mx = wred_max(v);
        if (lane == 0) red[wv] = mx;
        __syncthreads();
        mx = fmaxf(fmaxf(red[0], red[1]), fmaxf(red[2], red[3]));
        float p = (tid < 197) ? __expf(v - mx) : 0.f;
        float sm = wred_sum(p);
        if (lane == 0) red[4 + wv] = sm;
        __syncthreads();
        float inv = 1.f / (red[4] + red[5] + red[6] + red[7]);
        if (tid < 197) sh[tid] = p * inv;
        __syncthreads();
        float beta = sh[196];
        int dec = clen[b] - 1; if (dec < 1) dec = 1;
        float act = (t < dec) ? 1.f : 0.f;
        if (tid < 196) alphas[(size_t)b * (T_ * L_) + (size_t)t * L_ + tid] = sh[tid] * act;
        if (tid == 196) betas[b * T_ + t] = beta * act;
        // ctx
        int c0 = tid * 2;
        int colterm = (c0 >> 5) * 512 + ((c0 & 31) >> 3) * 128 + (c0 & 7);
        float cx0 = 0.f, cx1 = 0.f;
        int rowbase = b * 196;
        for (int l = 0; l < 196; l++) {
          int row = rowbase + l;
          size_t addr = (size_t)(row >> 4) * 8192 + (size_t)((row & 15) * 8) + colterm;
          unsigned pv = *(const unsigned*)(const void*)(enc_p + addr);
          float al = sh[l];
          cx0 += al * b2f((short)(pv & 0xffff));
          cx1 += al * b2f((short)(pv >> 16));
        }
        const float* sprev = sbuf + (size_t)(t & 1) * 65536;
        cx0 += beta * sprev[b * 512 + c0];
        cx1 += beta * sprev[b * 512 + c0 + 1];
        bf16* pA = projA + (size_t)t * 131072;
        size_t po = pidx(b, 512 + c0, 1024);
        pA[po] = f2b(cx0);
        pA[po + 1] = f2b(cx1);
      }
    }
    if (tt < T_) {
      gbar(bar);
      // ---- P3: agsw(tt) = [h|s] @ WT_a^T + bax, waves 0-1 of every block
      if (wv < 2) {
        int job = blk * 2 + wv;   // 0..511
        int mi = job >> 6;        // 0..7
        int ni = job & 63;        // 0..63
        f32x4 a3 = f32x4{0.f, 0.f, 0.f, 0.f};
        const bf16* ap = Aag + ((size_t)mi * 32) * 512 + lane * 8;
        const bf16* bp = WT_a + ((size_t)ni * 32) * 512 + lane * 8;
#pragma unroll 4
        for (int kt = 0; kt < 32; kt++) {
          bf16x8 af = *(const bf16x8*)(const void*)(ap + (size_t)kt * 512);
          bf16x8 bf_ = *(const bf16x8*)(const void*)(bp + (size_t)kt * 512);
          a3 = __builtin_amdgcn_mfma_f32_16x16x32_bf16(af, bf_, a3, 0, 0, 0);
        }
        int n = ni * 16 + r16;
#pragma unroll
        for (int r = 0; r < 4; r++) {
          int m = mi * 16 + kg * 4 + r;
          agswb[m * 1024 + n] = a3[r] + bax[n];
        }
      }
      gbar(bar);
    }
  }
}

enum { EPI_F32 = 0, EPI_BF16 = 1, EPI_INIT = 2, EPI_PROJ = 3, EPI_OUT = 4 };

// C = A (MxK packed) @ BT^T (BT: NxK packed), + bias.
template<int MFRAG, int NFRAG, int EPI>
__global__ __launch_bounds__(256) void gemm_pk(
    const bf16* __restrict__ A, const bf16* __restrict__ BT,
    const float* __restrict__ bias, void* __restrict__ Cp,
    const bf16* __restrict__ auxA, float* __restrict__ auxB,
    int M, int N, int K, int ldc, int R0)
{
  const int lane = threadIdx.x & 63;
  const int wv = threadIdx.x >> 6;
  const int r16 = lane & 15;
  const int kg = lane >> 4;
  const int m0 = blockIdx.x * (MFRAG * 16);
  const int n0 = blockIdx.y * (NFRAG * 64) + wv * (NFRAG * 16);
  const int KT = K >> 5;

  f32x4 acc[MFRAG][NFRAG];
#pragma unroll
  for (int i = 0; i < MFRAG; i++)
#pragma unroll
    for (int j = 0; j < NFRAG; j++) acc[i][j] = f32x4{0.f, 0.f, 0.f, 0.f};

  const bf16* ap = A + (size_t)(m0 >> 4) * KT * 512 + lane * 8;
  const bf16* bp = BT + (size_t)(n0 >> 4) * KT * 512 + lane * 8;

#pragma unroll 4
  for (int kt = 0; kt < KT; kt++) {
    bf16x8 af[MFRAG], bfr[NFRAG];
#pragma unroll
    for (int i = 0; i < MFRAG; i++)
      af[i] = *(const bf16x8*)(const void*)(ap + ((size_t)i * KT + kt) * 512);
#pragma unroll
    for (int j = 0; j < NFRAG; j++)
      bfr[j] = *(const bf16x8*)(const void*)(bp + ((size_t)j * KT + kt) * 512);
#pragma unroll
    for (int i = 0; i < MFRAG; i++)
#pragma unroll
      for (int j = 0; j < NFRAG; j++)
        acc[i][j] = __builtin_amdgcn_mfma_f32_16x16x32_bf16(af[i], bfr[j], acc[i][j], 0, 0, 0);
  }

#pragma unroll
  for (int i = 0; i < MFRAG; i++)
#pragma unroll
    for (int j = 0; j < NFRAG; j++)
#pragma unroll
      for (int r = 0; r < 4; r++) {
        int m = m0 + i * 16 + kg * 4 + r;
        int n = n0 + j * 16 + r16;
        if (n >= N) continue;
        float v = acc[i][j][r] + bias[n];
        if constexpr (EPI == EPI_F32) {
          ((float*)Cp)[(size_t)m * ldc + n] = v;
        } else if constexpr (EPI == EPI_BF16) {
          ((bf16*)Cp)[(size_t)m * ldc + n] = f2b(v);
        } else if constexpr (EPI == EPI_INIT) {
          float tv = tanhf(v);
          if (n < 512) ((bf16*)Cp)[pidx(m, 512 + n, 1024)] = f2b(tv);  // h0 -> A1[0]
          else auxB[(size_t)m * 512 + (n - 512)] = tv;                 // c0 (f32)
        } else if constexpr (EPI == EPI_PROJ) {
          int t = m >> 7, b = m & 127;
          v += b2f(((const short*)auxA)[(size_t)t * 131072 + pidx(b, n, 1024)]);  // + x
          ((bf16*)Cp)[pidx(m, n, 512)] = f2b(v);
        } else {  // EPI_OUT: preds[b, t, n], row = t*128+b
          int t = m >> 7, b = m & 127;
          ((float*)Cp)[(size_t)b * (T_ * V_) + (size_t)t * V_ + n] = v;
        }
      }
}

// Packed-transpose: dst (nrows x K packed) = [top; bot]^T with zero padding.
__global__ void trans_pack(const float* __restrict__ top, const float* __restrict__ bot,
                           bf16* __restrict__ dst, int ncols, long nElem8, int ktop, int K)
{
  int KT = K >> 5;
  for (long t8 = (long)blockIdx.x * blockDim.x + threadIdx.x; t8 < nElem8;
       t8 += (long)gridDim.x * blockDim.x) {
    int r = (int)(t8 & 15);
    int kg = (int)((t8 >> 4) & 3);
    long tile = t8 >> 6;
    int kt = (int)(tile % KT);
    int rt = (int)(tile / KT);
    int n = rt * 16 + r;
    int kb = kt * 32 + kg * 8;
    bf16x8 out;
#pragma unroll
    for (int j = 0; j < 8; j++) {
      int k = kb + j;
      float v = 0.f;
      if (n < ncols) {
        if (k < ktop) { if (top) v = top[(size_t)k * ncols + n]; }
        else if (bot) { v = bot[(size_t)(k - ktop) * ncols + n]; }
      }
      out[j] = f2bs(v);
    }
    *(bf16x8*)(void*)(dst + t8 * 8) = out;
  }
}

// enc (f32 row-major, 25088x512) -> enc_p (bf16 packed)
__global__ void conv_pack(const float* __restrict__ src, bf16* __restrict__ dst, long nElem8)
{
  for (long t8 = (long)blockIdx.x * blockDim.x + threadIdx.x; t8 < nElem8;
       t8 += (long)gridDim.x * blockDim.x) {
    int r = (int)(t8 & 15);
    int kg = (int)((t8 >> 4) & 3);
    long tile = t8 >> 6;
    int kt = (int)(tile & 15);           // KT = 16 (K=512)
    int rt = (int)(tile >> 4);
    const float* s = src + ((size_t)(rt * 16 + r)) * 512 + kt * 32 + kg * 8;
    bf16x8 out;
#pragma unroll
    for (int j = 0; j < 8; j++) out[j] = f2bs(s[j]);
    *(bf16x8*)(void*)(dst + t8 * 8) = out;
  }
}

__global__ void bias_comb(const float* __restrict__ b_lstm, const float* __restrict__ b_s,
                          const float* __restrict__ b_g, const float* __restrict__ b_sa,
                          const float* __restrict__ b_Lh, const float* __restrict__ b_Lz,
                          const float* __restrict__ b_ih, const float* __restrict__ b_ic,
                          float* __restrict__ bg, float* __restrict__ ba,
                          float* __restrict__ bp, float* __restrict__ bi)
{
  int i = blockIdx.x * blockDim.x + threadIdx.x;
  if (i < 2560) bg[i] = (i < 2048) ? b_lstm[i] : b_s[i - 2048];
  if (i < 1024) ba[i] = (i < 512) ? b_g[i] : b_sa[i - 512];
  if (i < 512)  bp[i] = b_Lh[i] + b_Lz[i];
  if (i < 1024) bi[i] = (i < 512) ? b_ih[i] : b_ic[i - 512];
}

__global__ __launch_bounds__(128) void mean_enc(const float* __restrict__ enc,
                                                bf16* __restrict__ mb)
{
  int b = blockIdx.x, c = blockIdx.y * 128 + threadIdx.x;
  float s = 0.f;
  for (int l = 0; l < L_; l++) s += enc[((size_t)b * L_ + l) * 512 + c];
  mb[pidx(b, c, 512)] = f2b(s * (1.f / (float)L_));
}

__global__ void gather_x(const float* __restrict__ emb, const int* __restrict__ caps,
                         bf16* __restrict__ A1)
{
  int tb = blockIdx.x;          // t*128 + b
  int t = tb >> 7, b = tb & 127;
  int word = caps[b * 26 + t];
  int c0 = threadIdx.x * 8;
  const float* src = emb + (size_t)word * 512 + c0;
  bf16* dst = A1 + (size_t)t * (128 * 1024) + pidx(b, c0, 1024);
  bf16x8 out;
#pragma unroll
  for (int j = 0; j < 8; j++) out[j] = f2bs(src[j]);
  *(bf16x8*)(void*)dst = out;
}

extern "C" void kernel_launch(void* const* d_in, const int* in_sizes, int n_in,
                              void* d_out, int out_size, void* d_ws, size_t ws_size,
                              hipStream_t stream)
{
  const float* enc      = (const float*)d_in[0];
  const int*   caps     = (const int*)d_in[1];
  const int*   clen     = (const int*)d_in[2];
  const float* emb      = (const float*)d_in[3];
  const float* W_ih     = (const float*)d_in[4];
  const float* W_hh     = (const float*)d_in[5];
  const float* b_lstm   = (const float*)d_in[6];
  const float* Wx_s     = (const float*)d_in[7];
  const float* Wh_s     = (const float*)d_in[8];
  const float* b_s      = (const float*)d_in[9];
  const float* W_v      = (const float*)d_in[10];
  const float* b_v      = (const float*)d_in[11];
  const float* W_g      = (const float*)d_in[12];
  const float* b_g      = (const float*)d_in[13];
  const float* W_s_att  = (const float*)d_in[14];
  const float* b_sa     = (const float*)d_in[15];
  const float* w_a      = (const float*)d_in[16];
  const float* W_init_h = (const float*)d_in[17];
  const float* b_init_h = (const float*)d_in[18];
  const float* W_init_c = (const float*)d_in[19];
  const float* b_init_c = (const float*)d_in[20];
  const float* W_Lh     = (const float*)d_in[21];
  const float* b_Lh     = (const float*)d_in[22];
  const float* W_Lz     = (const float*)d_in[23];
  const float* b_Lz     = (const float*)d_in[24];
  const float* W_Lo     = (const float*)d_in[25];
  const float* b_Lo     = (const float*)d_in[26];

  float* preds  = (float*)d_out;
  float* alphas = preds + (size_t)B_ * T_ * V_;
  float* betas  = alphas + (size_t)B_ * T_ * L_;

  char* ws = (char*)d_ws;
  size_t off = 0;
  auto alloc = [&](size_t bytes) -> void* {
    void* p = ws + off;
    off = (off + bytes + 255) & ~(size_t)255;
    return p;
  };
  bf16*  enc_p  = (bf16*)alloc((size_t)B_ * L_ * 512 * 2);
  bf16*  attv_b = (bf16*)alloc((size_t)B_ * L_ * 512 * 2);
  bf16*  WT_g   = (bf16*)alloc((size_t)2560 * 1024 * 2);
  bf16*  WT_a   = (bf16*)alloc((size_t)1024 * 1024 * 2);
  bf16*  WT_p   = (bf16*)alloc((size_t)512 * 1024 * 2);
  bf16*  WT_lo  = (bf16*)alloc((size_t)10240 * 512 * 2);
  bf16*  WT_v   = (bf16*)alloc((size_t)512 * 512 * 2);
  bf16*  WT_i   = (bf16*)alloc((size_t)1024 * 512 * 2);
  float* bgx    = (float*)alloc(2560 * 4);
  float* bax    = (float*)alloc(1024 * 4);
  float* bpx    = (float*)alloc(512 * 4);
  float* bix    = (float*)alloc(1024 * 4);
  bf16*  mean_b = (bf16*)alloc(128 * 512 * 2);
  bf16*  A1     = (bf16*)alloc((size_t)(T_ + 1) * 128 * 1024 * 2);
  bf16*  projA  = (bf16*)alloc((size_t)T_ * 128 * 1024 * 2);
  bf16*  projb  = (bf16*)alloc((size_t)T_ * 128 * 512 * 2);
  float* agswb  = (float*)alloc((size_t)128 * 1024 * 4);
  bf16*  Aag    = (bf16*)alloc(128 * 1024 * 2);
  float* cbuf   = (float*)alloc(128 * 512 * 4);
  float* sbuf   = (float*)alloc(2 * 128 * 512 * 4);
  unsigned* bar = (unsigned*)alloc(4096);
  if (off > ws_size) return;  // loud validation failure if ws too small

  hipMemsetAsync(bar, 0, 4096, stream);

  // ---- prep ----
  bias_comb<<<dim3(10), dim3(256), 0, stream>>>(b_lstm, b_s, b_g, b_sa, b_Lh, b_Lz,
                                                b_init_h, b_init_c, bgx, bax, bpx, bix);
  auto TP = [&](const float* top, const float* bot, bf16* dst, int ncols, int nrows,
                int ktop, int K) {
    long n8 = (long)nrows * K / 8;
    int blocks = (int)((n8 + 255) / 256);
    if (blocks > 4096) blocks = 4096;
    trans_pack<<<dim3(blocks), dim3(256), 0, stream>>>(top, bot, dst, ncols, n8, ktop, K);
  };
  TP(W_ih, W_hh, WT_g, 2048, 2048, 512, 1024);
  TP(Wx_s, Wh_s, WT_g + (size_t)2048 * 1024, 512, 512, 512, 1024);
  TP(W_Lh, W_Lz, WT_p, 512, 512, 512, 1024);
  TP(W_g, nullptr, WT_a, 512, 512, 512, 1024);
  TP(nullptr, W_s_att, WT_a + (size_t)512 * 1024, 512, 512, 512, 1024);
  TP(W_Lo, nullptr, WT_lo, 10000, 10240, 512, 512);
  TP(W_v, nullptr, WT_v, 512, 512, 512, 512);
  TP(W_init_h, nullptr, WT_i, 512, 512, 512, 512);
  TP(W_init_c, nullptr, WT_i + (size_t)512 * 512, 512, 512, 512, 512);
  conv_pack<<<dim3(4096), dim3(256), 0, stream>>>(enc, enc_p, (long)B_ * L_ * 512 / 8);
  mean_enc<<<dim3(128, 4), dim3(128), 0, stream>>>(enc, mean_b);
  gather_x<<<dim3(T_ * 128), dim3(64), 0, stream>>>(emb, caps, A1);

  // h0 -> A1[0] h-slot (packed bf16), c0 -> cbuf (f32)
  gemm_pk<1, 1, EPI_INIT><<<dim3(8, 16), dim3(256), 0, stream>>>(
      mean_b, WT_i, bix, (void*)A1, nullptr, cbuf, 128, 1024, 512, 0, 0);
  // att_v = enc @ W_v + b_v   (bf16 row-major out)
  gemm_pk<4, 2, EPI_BF16><<<dim3(392, 4), dim3(256), 0, stream>>>(
      enc_p, WT_v, b_v, attv_b, nullptr, nullptr, B_ * L_, 512, 512, 512, 0);

  // ---- persistent 25-step scan ----
  scan_fused<<<dim3(NBLK), dim3(256), 0, stream>>>(
      A1, WT_g, bgx, cbuf, sbuf, Aag, projA, WT_a, bax, agswb,
      attv_b, w_a, enc_p, clen, alphas, betas, bar);

  // proj = x + [h|ctx] @ [W_Lh;W_Lz] + b   (3200 x 512 x 1024, packed out)
  gemm_pk<4, 2, EPI_PROJ><<<dim3(50, 4), dim3(256), 0, stream>>>(
      projA, WT_p, bpx, projb, (const bf16*)A1, nullptr, T_ * 128, 512, 1024, 0, 0);
  // preds = proj @ W_Lo + b_Lo  (3200 x 10000 x 512)
  gemm_pk<4, 4, EPI_OUT><<<dim3(50, 40), dim3(256), 0, stream>>>(
      projb, WT_lo, b_Lo, preds, nullptr, nullptr, T_ * 128, V_, 512, 0, 0);
}

// Round 5
// 1819.989 us; speedup vs baseline: 1.2646x; 1.2646x over previous
//
#include <hip/hip_runtime.h>
#include <hip/hip_bf16.h>
#include <cstdint>
#include <cstddef>

using bf16 = __hip_bfloat16;
typedef __attribute__((ext_vector_type(4))) float f32x4;
typedef __attribute__((ext_vector_type(8))) short bf16x8;

#define B_ 128
#define L_ 196
#define T_ 25
#define V_ 10000
#define NBLK 256

__device__ __forceinline__ float b2f(short s) {
  unsigned u = ((unsigned)(unsigned short)s) << 16;
  return __uint_as_float(u);
}
__device__ __forceinline__ bf16 f2b(float f) { return __float2bfloat16(f); }
__device__ __forceinline__ short f2bs(float f) {
  return __builtin_bit_cast(short, __float2bfloat16(f));
}
__device__ __forceinline__ float sigf(float x) { return 1.f / (1.f + __expf(-x)); }
__device__ __forceinline__ float tanh_fast(float x) { return 1.f - 2.f / (1.f + __expf(2.f * x)); }

// ---- relaxed agent-scope (cross-XCD coherent, no L2 flush) access helpers ----
__device__ __forceinline__ void cst_u32(unsigned* p, unsigned v) {
  __hip_atomic_store(p, v, __ATOMIC_RELAXED, __HIP_MEMORY_SCOPE_AGENT);
}
__device__ __forceinline__ unsigned cld_u32(const unsigned* p) {
  return __hip_atomic_load((unsigned*)p, __ATOMIC_RELAXED, __HIP_MEMORY_SCOPE_AGENT);
}
__device__ __forceinline__ void cst_f32(float* p, float v) {
  __hip_atomic_store(p, v, __ATOMIC_RELAXED, __HIP_MEMORY_SCOPE_AGENT);
}
__device__ __forceinline__ float cld_f32(const float* p) {
  return __hip_atomic_load((float*)p, __ATOMIC_RELAXED, __HIP_MEMORY_SCOPE_AGENT);
}
__device__ __forceinline__ unsigned long long cld_u64(const void* p) {
  return __hip_atomic_load((unsigned long long*)p, __ATOMIC_RELAXED,
                           __HIP_MEMORY_SCOPE_AGENT);
}
__device__ __forceinline__ bf16x8 cld_frag(const bf16* p) {
  union { unsigned long long u[2]; bf16x8 v; } x;
  x.u[0] = cld_u64(p);
  x.u[1] = cld_u64(p + 4);
  return x.v;
}

// Fragment-packed layout: 16x32 tiles, tile-row-major; element (r,c) at
// (((r>>4)*KT + (c>>5))*64 + ((c&31)>>3)*16 + (r&15))*8 + (c&7).
__device__ __forceinline__ size_t pidx(int row, int col, int K) {
  int KT = K >> 5;
  return (((size_t)(row >> 4) * KT + (col >> 5)) * 64 +
          (size_t)(((col & 31) >> 3) * 16 + (row & 15))) * 8 + (col & 7);
}

__device__ __forceinline__ float wred_sum(float x) {
#pragma unroll
  for (int off = 32; off >= 1; off >>= 1) x += __shfl_xor(x, off, 64);
  return x;
}
__device__ __forceinline__ float wred_max(float x) {
#pragma unroll
  for (int off = 32; off >= 1; off >>= 1) x = fmaxf(x, __shfl_xor(x, off, 64));
  return x;
}

// ---- two-level grid barrier: relaxed atomics ONLY (no L2 inv/wb) ----
__device__ __forceinline__ void gbar(unsigned* bs) {
  __syncthreads();               // drains this block's vmem (compiler emits vmcnt(0))
  if (threadIdx.x == 0) {
    asm volatile("s_waitcnt vmcnt(0)" ::: "memory");
    unsigned* lcnt = bs;         // 16 shards, 128B apart
    unsigned* cnt  = bs + 512;
    unsigned* gen  = bs + 544;
    unsigned g = cld_u32(gen);
    int grp = (int)(blockIdx.x & 15u);
    unsigned a = __hip_atomic_fetch_add(&lcnt[grp * 32], 1u, __ATOMIC_RELAXED,
                                        __HIP_MEMORY_SCOPE_AGENT);
    bool rel = false;
    if ((a & 15u) == 15u) {
      unsigned b = __hip_atomic_fetch_add(cnt, 1u, __ATOMIC_RELAXED,
                                          __HIP_MEMORY_SCOPE_AGENT);
      if ((b & 15u) == 15u) {
        cst_u32(gen, g + 1u);
        rel = true;
      }
    }
    if (!rel) {
      while (cld_u32(gen) == g) __builtin_amdgcn_s_sleep(1);
    }
  }
  __syncthreads();
}

// ---- persistent scan kernel: 25 steps, 2 grid barriers per step ----
__global__ __launch_bounds__(256) void scan_fused(
    bf16* __restrict__ A1,          // (T_+1) x (128x1024 packed): [x | h]
    const bf16* __restrict__ WT_g,  // 2560x1024 packed
    const float* __restrict__ bgx,
    float* __restrict__ cbuf,       // 128x512 f32 (block-private)
    float* __restrict__ sbuf,       // 2 x 128x512 f32 ping-pong (coherent)
    bf16* __restrict__ Aag,         // 128x1024 packed [h|s] (coherent)
    bf16* __restrict__ projA,       // T_ x (128x1024 packed): [h | ctx]
    const bf16* __restrict__ WT_a,  // 1024x1024 packed
    const float* __restrict__ bax,
    float* __restrict__ agswb,      // 128x1024 f32 (coherent)
    const bf16* __restrict__ attv,  // 25088x512 row-major bf16
    const float* __restrict__ w_a,
    const bf16* __restrict__ enc_r, // 25088x512 row-major bf16
    const int* __restrict__ clen,
    float* __restrict__ alphas, float* __restrict__ betas,
    unsigned* __restrict__ bar)
{
  const int blk = blockIdx.x;
  const int tid = threadIdx.x;
  const int wv = tid >> 6, lane = tid & 63;
  const int r16 = lane & 15, kg = lane >> 4;
  __shared__ f32x4 pacc[4][10][64];   // 40 KB split-K partials
  __shared__ float sh[200];
  __shared__ float red[8];

  for (int tt = 0; tt <= T_; ++tt) {
    if (blk >= 128) {
      // ---- P1: gates GEMM (t=tt) + fused LSTM pointwise; 4 waves split kt ----
      if (tt < T_) {
        int job = blk - 128;
        int mi = job >> 5;              // 0..3 (32-row group)
        int di = job & 31;              // 0..31 (16-col d group)
        const bf16* A1t = A1 + (size_t)tt * 131072;
        f32x4 acc[2][5];
#pragma unroll
        for (int i = 0; i < 2; i++)
#pragma unroll
          for (int g = 0; g < 5; g++) acc[i][g] = f32x4{0.f, 0.f, 0.f, 0.f};
        const bf16* ap0 = A1t + (size_t)(mi * 2 + 0) * 16384 + lane * 8;
        const bf16* ap1 = A1t + (size_t)(mi * 2 + 1) * 16384 + lane * 8;
        const bf16* bp0 = WT_g + (size_t)(0 * 32 + di) * 16384 + lane * 8;
        const bf16* bp1 = WT_g + (size_t)(1 * 32 + di) * 16384 + lane * 8;
        const bf16* bp2 = WT_g + (size_t)(2 * 32 + di) * 16384 + lane * 8;
        const bf16* bp3 = WT_g + (size_t)(3 * 32 + di) * 16384 + lane * 8;
        const bf16* bp4 = WT_g + (size_t)(4 * 32 + di) * 16384 + lane * 8;
        if (wv < 2) {
          // kt 0..15 : x-half, read-only, normal cached loads
#pragma unroll 4
          for (int kk = 0; kk < 8; kk++) {
            size_t o = (size_t)(wv * 8 + kk) * 512;
            bf16x8 a0 = *(const bf16x8*)(const void*)(ap0 + o);
            bf16x8 a1 = *(const bf16x8*)(const void*)(ap1 + o);
            bf16x8 b0 = *(const bf16x8*)(const void*)(bp0 + o);
            bf16x8 b1 = *(const bf16x8*)(const void*)(bp1 + o);
            bf16x8 b2 = *(const bf16x8*)(const void*)(bp2 + o);
            bf16x8 b3 = *(const bf16x8*)(const void*)(bp3 + o);
            bf16x8 b4 = *(const bf16x8*)(const void*)(bp4 + o);
            acc[0][0] = __builtin_amdgcn_mfma_f32_16x16x32_bf16(a0, b0, acc[0][0], 0, 0, 0);
            acc[1][0] = __builtin_amdgcn_mfma_f32_16x16x32_bf16(a1, b0, acc[1][0], 0, 0, 0);
            acc[0][1] = __builtin_amdgcn_mfma_f32_16x16x32_bf16(a0, b1, acc[0][1], 0, 0, 0);
            acc[1][1] = __builtin_amdgcn_mfma_f32_16x16x32_bf16(a1, b1, acc[1][1], 0, 0, 0);
            acc[0][2] = __builtin_amdgcn_mfma_f32_16x16x32_bf16(a0, b2, acc[0][2], 0, 0, 0);
            acc[1][2] = __builtin_amdgcn_mfma_f32_16x16x32_bf16(a1, b2, acc[1][2], 0, 0, 0);
            acc[0][3] = __builtin_amdgcn_mfma_f32_16x16x32_bf16(a0, b3, acc[0][3], 0, 0, 0);
            acc[1][3] = __builtin_amdgcn_mfma_f32_16x16x32_bf16(a1, b3, acc[1][3], 0, 0, 0);
            acc[0][4] = __builtin_amdgcn_mfma_f32_16x16x32_bf16(a0, b4, acc[0][4], 0, 0, 0);
            acc[1][4] = __builtin_amdgcn_mfma_f32_16x16x32_bf16(a1, b4, acc[1][4], 0, 0, 0);
          }
        } else {
          // kt 16..31 : h-half, written by P1 last step -> coherent loads
#pragma unroll 4
          for (int kk = 0; kk < 8; kk++) {
            size_t o = (size_t)(wv * 8 + kk) * 512;
            bf16x8 a0 = cld_frag(ap0 + o);
            bf16x8 a1 = cld_frag(ap1 + o);
            bf16x8 b0 = *(const bf16x8*)(const void*)(bp0 + o);
            bf16x8 b1 = *(const bf16x8*)(const void*)(bp1 + o);
            bf16x8 b2 = *(const bf16x8*)(const void*)(bp2 + o);
            bf16x8 b3 = *(const bf16x8*)(const void*)(bp3 + o);
            bf16x8 b4 = *(const bf16x8*)(const void*)(bp4 + o);
            acc[0][0] = __builtin_amdgcn_mfma_f32_16x16x32_bf16(a0, b0, acc[0][0], 0, 0, 0);
            acc[1][0] = __builtin_amdgcn_mfma_f32_16x16x32_bf16(a1, b0, acc[1][0], 0, 0, 0);
            acc[0][1] = __builtin_amdgcn_mfma_f32_16x16x32_bf16(a0, b1, acc[0][1], 0, 0, 0);
            acc[1][1] = __builtin_amdgcn_mfma_f32_16x16x32_bf16(a1, b1, acc[1][1], 0, 0, 0);
            acc[0][2] = __builtin_amdgcn_mfma_f32_16x16x32_bf16(a0, b2, acc[0][2], 0, 0, 0);
            acc[1][2] = __builtin_amdgcn_mfma_f32_16x16x32_bf16(a1, b2, acc[1][2], 0, 0, 0);
            acc[0][3] = __builtin_amdgcn_mfma_f32_16x16x32_bf16(a0, b3, acc[0][3], 0, 0, 0);
            acc[1][3] = __builtin_amdgcn_mfma_f32_16x16x32_bf16(a1, b3, acc[1][3], 0, 0, 0);
            acc[0][4] = __builtin_amdgcn_mfma_f32_16x16x32_bf16(a0, b4, acc[0][4], 0, 0, 0);
            acc[1][4] = __builtin_amdgcn_mfma_f32_16x16x32_bf16(a1, b4, acc[1][4], 0, 0, 0);
          }
        }
#pragma unroll
        for (int i = 0; i < 2; i++)
#pragma unroll
          for (int g = 0; g < 5; g++) pacc[wv][i * 5 + g][lane] = acc[i][g];
        __syncthreads();
        if (wv == 0) {
          int d = di * 16 + r16;
          float bi0 = bgx[d], bi1 = bgx[512 + d], bi2 = bgx[1024 + d];
          float bi3 = bgx[1536 + d], bi4 = bgx[2048 + d];
          bf16* hnext = A1 + (size_t)(tt + 1) * 131072;
          bf16* pA = projA + (size_t)tt * 131072;
          float* sb = sbuf + (size_t)(tt & 1) * 65536;
#pragma unroll
          for (int i = 0; i < 2; i++) {
            f32x4 g0 = pacc[0][i * 5 + 0][lane] + pacc[1][i * 5 + 0][lane] +
                       pacc[2][i * 5 + 0][lane] + pacc[3][i * 5 + 0][lane];
            f32x4 g1 = pacc[0][i * 5 + 1][lane] + pacc[1][i * 5 + 1][lane] +
                       pacc[2][i * 5 + 1][lane] + pacc[3][i * 5 + 1][lane];
            f32x4 g2 = pacc[0][i * 5 + 2][lane] + pacc[1][i * 5 + 2][lane] +
                       pacc[2][i * 5 + 2][lane] + pacc[3][i * 5 + 2][lane];
            f32x4 g3 = pacc[0][i * 5 + 3][lane] + pacc[1][i * 5 + 3][lane] +
                       pacc[2][i * 5 + 3][lane] + pacc[3][i * 5 + 3][lane];
            f32x4 g4 = pacc[0][i * 5 + 4][lane] + pacc[1][i * 5 + 4][lane] +
                       pacc[2][i * 5 + 4][lane] + pacc[3][i * 5 + 4][lane];
#pragma unroll
            for (int r = 0; r < 4; r++) {
              int m = mi * 32 + i * 16 + kg * 4 + r;
              float cn = sigf(g1[r] + bi1) * cbuf[m * 512 + d] +
                         sigf(g0[r] + bi0) * tanh_fast(g2[r] + bi2);
              float tcn = tanh_fast(cn);
              float hn = sigf(g3[r] + bi3) * tcn;
              float ss = sigf(g4[r] + bi4) * tcn;
              cbuf[m * 512 + d] = cn;
              cst_f32(&sb[m * 512 + d], ss);
              size_t plo = pidx(m, d, 1024), phi = pidx(m, 512 + d, 1024);
              pA[plo] = f2b(hn);                      // tail-kernel consumer
              float hn1 = __shfl_down(hn, 1);
              float ss1 = __shfl_down(ss, 1);
              if (!(r16 & 1)) {
                unsigned hp = (unsigned)(unsigned short)f2bs(hn) |
                              ((unsigned)(unsigned short)f2bs(hn1) << 16);
                unsigned sp = (unsigned)(unsigned short)f2bs(ss) |
                              ((unsigned)(unsigned short)f2bs(ss1) << 16);
                cst_u32((unsigned*)(void*)(Aag + plo), hp);
                cst_u32((unsigned*)(void*)(Aag + phi), sp);
                cst_u32((unsigned*)(void*)(hnext + phi), hp);
              }
            }
          }
        }
      }
    } else {
      // ---- P4: attention for t = tt-1; one block per batch element ----
      if (tt >= 1) {
        int t = tt - 1, b = blk;
        const float* ag = agswb + b * 1024;
        int a0 = lane * 8;
        float ag8[8], wa8[8];
#pragma unroll
        for (int j = 0; j < 8; j++) { ag8[j] = cld_f32(ag + a0 + j); wa8[j] = w_a[a0 + j]; }
        for (int l = wv; l < 197; l += 4) {
          float part = 0.f;
          if (l < 196) {
            bf16x8 av = *(const bf16x8*)(const void*)(attv + ((size_t)(b * 196 + l)) * 512 + a0);
#pragma unroll
            for (int j = 0; j < 8; j++) part += wa8[j] * tanh_fast(b2f(av[j]) + ag8[j]);
          } else {
#pragma unroll
            for (int j = 0; j < 8; j++)
              part += wa8[j] * tanh_fast(cld_f32(ag + 512 + a0 + j) + ag8[j]);
          }
          part = wred_sum(part);
          if (lane == 0) sh[l] = part;
        }
        __syncthreads();
        float v = (tid < 197) ? sh[tid] : -1e30f;
        float mx = wred_max(v);
        if (lane == 0) red[wv] = mx;
        __syncthreads();
        mx = fmaxf(fmaxf(red[0], red[1]), fmaxf(red[2], red[3]));
        float p = (tid < 197) ? __expf(v - mx) : 0.f;
        float sm = wred_sum(p);
        if (lane == 0) red[4 + wv] = sm;
        __syncthreads();
        float inv = 1.f / (red[4] + red[5] + red[6] + red[7]);
        if (tid < 197) sh[tid] = p * inv;
        __syncthreads();
        float beta = sh[196];
        int dec = clen[b] - 1; if (dec < 1) dec = 1;
        float act = (t < dec) ? 1.f : 0.f;
        if (tid < 196) alphas[(size_t)b * (T_ * L_) + (size_t)t * L_ + tid] = sh[tid] * act;
        if (tid == 196) betas[b * T_ + t] = beta * act;
        // ctx: coalesced row-major enc reads (wave reads 256B contiguous per l)
        int c0 = tid * 2;
        const unsigned* ep = (const unsigned*)(const void*)(enc_r) +
                             (((size_t)b * 196) * 512 + c0) / 2;
        float cx0 = 0.f, cx1 = 0.f;
#pragma unroll 4
        for (int l = 0; l < 196; l++) {
          unsigned pv = ep[(size_t)l * 256];
          float al = sh[l];
          cx0 += al * b2f((short)(pv & 0xffff));
          cx1 += al * b2f((short)(pv >> 16));
        }
        const float* sprev = sbuf + (size_t)(t & 1) * 65536;
        cx0 += beta * cld_f32(sprev + b * 512 + c0);
        cx1 += beta * cld_f32(sprev + b * 512 + c0 + 1);
        bf16* pA = projA + (size_t)t * 131072;
        size_t po = pidx(b, 512 + c0, 1024);
        pA[po] = f2b(cx0);
        pA[po + 1] = f2b(cx1);
      }
    }
    if (tt < T_) {
      gbar(bar);
      // ---- P3: agsw(tt) = [h|s] @ WT_a^T + bax; waves 0-1 of every block ----
      if (wv < 2) {
        int job = blk * 2 + wv;   // 0..511
        int mi = job >> 6;        // 0..7
        int ni = job & 63;        // 0..63
        f32x4 a3 = f32x4{0.f, 0.f, 0.f, 0.f};
        const bf16* ap = Aag + (size_t)mi * 16384 + lane * 8;
        const bf16* bp = WT_a + (size_t)ni * 16384 + lane * 8;
#pragma unroll 4
        for (int kt = 0; kt < 32; kt++) {
          bf16x8 af = cld_frag(ap + (size_t)kt * 512);
          bf16x8 bf_ = *(const bf16x8*)(const void*)(bp + (size_t)kt * 512);
          a3 = __builtin_amdgcn_mfma_f32_16x16x32_bf16(af, bf_, a3, 0, 0, 0);
        }
        int n = ni * 16 + r16;
#pragma unroll
        for (int r = 0; r < 4; r++) {
          int m = mi * 16 + kg * 4 + r;
          cst_f32(&agswb[m * 1024 + n], a3[r] + bax[n]);
        }
      }
      gbar(bar);
    }
  }
}

enum { EPI_F32 = 0, EPI_BF16 = 1, EPI_INIT = 2, EPI_PROJ = 3, EPI_OUT = 4 };

// C = A (MxK packed) @ BT^T (BT: NxK packed), + bias.
template<int MFRAG, int NFRAG, int EPI>
__global__ __launch_bounds__(256) void gemm_pk(
    const bf16* __restrict__ A, const bf16* __restrict__ BT,
    const float* __restrict__ bias, void* __restrict__ Cp,
    const bf16* __restrict__ auxA, float* __restrict__ auxB,
    int M, int N, int K, int ldc, int R0)
{
  const int lane = threadIdx.x & 63;
  const int wv = threadIdx.x >> 6;
  const int r16 = lane & 15;
  const int kg = lane >> 4;
  const int m0 = blockIdx.x * (MFRAG * 16);
  const int n0 = blockIdx.y * (NFRAG * 64) + wv * (NFRAG * 16);
  const int KT = K >> 5;

  f32x4 acc[MFRAG][NFRAG];
#pragma unroll
  for (int i = 0; i < MFRAG; i++)
#pragma unroll
    for (int j = 0; j < NFRAG; j++) acc[i][j] = f32x4{0.f, 0.f, 0.f, 0.f};

  const bf16* ap = A + (size_t)(m0 >> 4) * KT * 512 + lane * 8;
  const bf16* bp = BT + (size_t)(n0 >> 4) * KT * 512 + lane * 8;

#pragma unroll 4
  for (int kt = 0; kt < KT; kt++) {
    bf16x8 af[MFRAG], bfr[NFRAG];
#pragma unroll
    for (int i = 0; i < MFRAG; i++)
      af[i] = *(const bf16x8*)(const void*)(ap + ((size_t)i * KT + kt) * 512);
#pragma unroll
    for (int j = 0; j < NFRAG; j++)
      bfr[j] = *(const bf16x8*)(const void*)(bp + ((size_t)j * KT + kt) * 512);
#pragma unroll
    for (int i = 0; i < MFRAG; i++)
#pragma unroll
      for (int j = 0; j < NFRAG; j++)
        acc[i][j] = __builtin_amdgcn_mfma_f32_16x16x32_bf16(af[i], bfr[j], acc[i][j], 0, 0, 0);
  }

#pragma unroll
  for (int i = 0; i < MFRAG; i++)
#pragma unroll
    for (int j = 0; j < NFRAG; j++)
#pragma unroll
      for (int r = 0; r < 4; r++) {
        int m = m0 + i * 16 + kg * 4 + r;
        int n = n0 + j * 16 + r16;
        if (n >= N) continue;
        float v = acc[i][j][r] + bias[n];
        if constexpr (EPI == EPI_F32) {
          ((float*)Cp)[(size_t)m * ldc + n] = v;
        } else if constexpr (EPI == EPI_BF16) {
          ((bf16*)Cp)[(size_t)m * ldc + n] = f2b(v);
        } else if constexpr (EPI == EPI_INIT) {
          float tv = tanhf(v);
          if (n < 512) ((bf16*)Cp)[pidx(m, 512 + n, 1024)] = f2b(tv);  // h0 -> A1[0]
          else auxB[(size_t)m * 512 + (n - 512)] = tv;                 // c0 (f32)
        } else if constexpr (EPI == EPI_PROJ) {
          int t = m >> 7, b = m & 127;
          v += b2f(((const short*)auxA)[(size_t)t * 131072 + pidx(b, n, 1024)]);  // + x
          ((bf16*)Cp)[pidx(m, n, 512)] = f2b(v);
        } else {  // EPI_OUT: preds[b, t, n], row = t*128+b
          int t = m >> 7, b = m & 127;
          ((float*)Cp)[(size_t)b * (T_ * V_) + (size_t)t * V_ + n] = v;
        }
      }
}

// Packed-transpose: dst (nrows x K packed) = [top; bot]^T with zero padding.
__global__ void trans_pack(const float* __restrict__ top, const float* __restrict__ bot,
                           bf16* __restrict__ dst, int ncols, long nElem8, int ktop, int K)
{
  int KT = K >> 5;
  for (long t8 = (long)blockIdx.x * blockDim.x + threadIdx.x; t8 < nElem8;
       t8 += (long)gridDim.x * blockDim.x) {
    int r = (int)(t8 & 15);
    int kg = (int)((t8 >> 4) & 3);
    long tile = t8 >> 6;
    int kt = (int)(tile % KT);
    int rt = (int)(tile / KT);
    int n = rt * 16 + r;
    int kb = kt * 32 + kg * 8;
    bf16x8 out;
#pragma unroll
    for (int j = 0; j < 8; j++) {
      int k = kb + j;
      float v = 0.f;
      if (n < ncols) {
        if (k < ktop) { if (top) v = top[(size_t)k * ncols + n]; }
        else if (bot) { v = bot[(size_t)(k - ktop) * ncols + n]; }
      }
      out[j] = f2bs(v);
    }
    *(bf16x8*)(void*)(dst + t8 * 8) = out;
  }
}

// enc (f32 row-major) -> enc_p (bf16 packed) AND enc_r (bf16 row-major)
__global__ void conv_pack(const float* __restrict__ src, bf16* __restrict__ dst,
                          bf16* __restrict__ dst_row, long nElem8)
{
  for (long t8 = (long)blockIdx.x * blockDim.x + threadIdx.x; t8 < nElem8;
       t8 += (long)gridDim.x * blockDim.x) {
    int r = (int)(t8 & 15);
    int kg = (int)((t8 >> 4) & 3);
    long tile = t8 >> 6;
    int kt = (int)(tile & 15);           // KT = 16 (K=512)
    int rt = (int)(tile >> 4);
    size_t rowoff = ((size_t)(rt * 16 + r)) * 512 + kt * 32 + kg * 8;
    const float* s = src + rowoff;
    bf16x8 out;
#pragma unroll
    for (int j = 0; j < 8; j++) out[j] = f2bs(s[j]);
    *(bf16x8*)(void*)(dst + t8 * 8) = out;
    *(bf16x8*)(void*)(dst_row + rowoff) = out;
  }
}

__global__ void bias_comb(const float* __restrict__ b_lstm, const float* __restrict__ b_s,
                          const float* __restrict__ b_g, const float* __restrict__ b_sa,
                          const float* __restrict__ b_Lh, const float* __restrict__ b_Lz,
                          const float* __restrict__ b_ih, const float* __restrict__ b_ic,
                          float* __restrict__ bg, float* __restrict__ ba,
                          float* __restrict__ bp, float* __restrict__ bi)
{
  int i = blockIdx.x * blockDim.x + threadIdx.x;
  if (i < 2560) bg[i] = (i < 2048) ? b_lstm[i] : b_s[i - 2048];
  if (i < 1024) ba[i] = (i < 512) ? b_g[i] : b_sa[i - 512];
  if (i < 512)  bp[i] = b_Lh[i] + b_Lz[i];
  if (i < 1024) bi[i] = (i < 512) ? b_ih[i] : b_ic[i - 512];
}

__global__ __launch_bounds__(128) void mean_enc(const float* __restrict__ enc,
                                                bf16* __restrict__ mb)
{
  int b = blockIdx.x, c = blockIdx.y * 128 + threadIdx.x;
  float s = 0.f;
  for (int l = 0; l < L_; l++) s += enc[((size_t)b * L_ + l) * 512 + c];
  mb[pidx(b, c, 512)] = f2b(s * (1.f / (float)L_));
}

__global__ void gather_x(const float* __restrict__ emb, const int* __restrict__ caps,
                         bf16* __restrict__ A1)
{
  int tb = blockIdx.x;          // t*128 + b
  int t = tb >> 7, b = tb & 127;
  int word = caps[b * 26 + t];
  int c0 = threadIdx.x * 8;
  const float* src = emb + (size_t)word * 512 + c0;
  bf16* dst = A1 + (size_t)t * (128 * 1024) + pidx(b, c0, 1024);
  bf16x8 out;
#pragma unroll
  for (int j = 0; j < 8; j++) out[j] = f2bs(src[j]);
  *(bf16x8*)(void*)dst = out;
}

extern "C" void kernel_launch(void* const* d_in, const int* in_sizes, int n_in,
                              void* d_out, int out_size, void* d_ws, size_t ws_size,
                              hipStream_t stream)
{
  const float* enc      = (const float*)d_in[0];
  const int*   caps     = (const int*)d_in[1];
  const int*   clen     = (const int*)d_in[2];
  const float* emb      = (const float*)d_in[3];
  const float* W_ih     = (const float*)d_in[4];
  const float* W_hh     = (const float*)d_in[5];
  const float* b_lstm   = (const float*)d_in[6];
  const float* Wx_s     = (const float*)d_in[7];
  const float* Wh_s     = (const float*)d_in[8];
  const float* b_s      = (const float*)d_in[9];
  const float* W_v      = (const float*)d_in[10];
  const float* b_v      = (const float*)d_in[11];
  const float* W_g      = (const float*)d_in[12];
  const float* b_g      = (const float*)d_in[13];
  const float* W_s_att  = (const float*)d_in[14];
  const float* b_sa     = (const float*)d_in[15];
  const float* w_a      = (const float*)d_in[16];
  const float* W_init_h = (const float*)d_in[17];
  const float* b_init_h = (const float*)d_in[18];
  const float* W_init_c = (const float*)d_in[19];
  const float* b_init_c = (const float*)d_in[20];
  const float* W_Lh     = (const float*)d_in[21];
  const float* b_Lh     = (const float*)d_in[22];
  const float* W_Lz     = (const float*)d_in[23];
  const float* b_Lz     = (const float*)d_in[24];
  const float* W_Lo     = (const float*)d_in[25];
  const float* b_Lo     = (const float*)d_in[26];

  float* preds  = (float*)d_out;
  float* alphas = preds + (size_t)B_ * T_ * V_;
  float* betas  = alphas + (size_t)B_ * T_ * L_;

  char* ws = (char*)d_ws;
  size_t off = 0;
  auto alloc = [&](size_t bytes) -> void* {
    void* p = ws + off;
    off = (off + bytes + 255) & ~(size_t)255;
    return p;
  };
  bf16*  enc_p  = (bf16*)alloc((size_t)B_ * L_ * 512 * 2);
  bf16*  enc_r  = (bf16*)alloc((size_t)B_ * L_ * 512 * 2);
  bf16*  attv_b = (bf16*)alloc((size_t)B_ * L_ * 512 * 2);
  bf16*  WT_g   = (bf16*)alloc((size_t)2560 * 1024 * 2);
  bf16*  WT_a   = (bf16*)alloc((size_t)1024 * 1024 * 2);
  bf16*  WT_p   = (bf16*)alloc((size_t)512 * 1024 * 2);
  bf16*  WT_lo  = (bf16*)alloc((size_t)10240 * 512 * 2);
  bf16*  WT_v   = (bf16*)alloc((size_t)512 * 512 * 2);
  bf16*  WT_i   = (bf16*)alloc((size_t)1024 * 512 * 2);
  float* bgx    = (float*)alloc(2560 * 4);
  float* bax    = (float*)alloc(1024 * 4);
  float* bpx    = (float*)alloc(512 * 4);
  float* bix    = (float*)alloc(1024 * 4);
  bf16*  mean_b = (bf16*)alloc(128 * 512 * 2);
  bf16*  A1     = (bf16*)alloc((size_t)(T_ + 1) * 128 * 1024 * 2);
  bf16*  projA  = (bf16*)alloc((size_t)T_ * 128 * 1024 * 2);
  bf16*  projb  = (bf16*)alloc((size_t)T_ * 128 * 512 * 2);
  float* agswb  = (float*)alloc((size_t)128 * 1024 * 4);
  bf16*  Aag    = (bf16*)alloc(128 * 1024 * 2);
  float* cbuf   = (float*)alloc(128 * 512 * 4);
  float* sbuf   = (float*)alloc(2 * 128 * 512 * 4);
  unsigned* bar = (unsigned*)alloc(4096);
  if (off > ws_size) return;  // loud validation failure if ws too small

  hipMemsetAsync(bar, 0, 4096, stream);

  // ---- prep ----
  bias_comb<<<dim3(10), dim3(256), 0, stream>>>(b_lstm, b_s, b_g, b_sa, b_Lh, b_Lz,
                                                b_init_h, b_init_c, bgx, bax, bpx, bix);
  auto TP = [&](const float* top, const float* bot, bf16* dst, int ncols, int nrows,
                int ktop, int K) {
    long n8 = (long)nrows * K / 8;
    int blocks = (int)((n8 + 255) / 256);
    if (blocks > 4096) blocks = 4096;
    trans_pack<<<dim3(blocks), dim3(256), 0, stream>>>(top, bot, dst, ncols, n8, ktop, K);
  };
  TP(W_ih, W_hh, WT_g, 2048, 2048, 512, 1024);
  TP(Wx_s, Wh_s, WT_g + (size_t)2048 * 1024, 512, 512, 512, 1024);
  TP(W_Lh, W_Lz, WT_p, 512, 512, 512, 1024);
  TP(W_g, nullptr, WT_a, 512, 512, 512, 1024);
  TP(nullptr, W_s_att, WT_a + (size_t)512 * 1024, 512, 512, 512, 1024);
  TP(W_Lo, nullptr, WT_lo, 10000, 10240, 512, 512);
  TP(W_v, nullptr, WT_v, 512, 512, 512, 512);
  TP(W_init_h, nullptr, WT_i, 512, 512, 512, 512);
  TP(W_init_c, nullptr, WT_i + (size_t)512 * 512, 512, 512, 512, 512);
  conv_pack<<<dim3(4096), dim3(256), 0, stream>>>(enc, enc_p, enc_r,
                                                  (long)B_ * L_ * 512 / 8);
  mean_enc<<<dim3(128, 4), dim3(128), 0, stream>>>(enc, mean_b);
  gather_x<<<dim3(T_ * 128), dim3(64), 0, stream>>>(emb, caps, A1);

  // h0 -> A1[0] h-slot (packed bf16), c0 -> cbuf (f32)
  gemm_pk<1, 1, EPI_INIT><<<dim3(8, 16), dim3(256), 0, stream>>>(
      mean_b, WT_i, bix, (void*)A1, nullptr, cbuf, 128, 1024, 512, 0, 0);
  // att_v = enc @ W_v + b_v   (bf16 row-major out)
  gemm_pk<4, 2, EPI_BF16><<<dim3(392, 4), dim3(256), 0, stream>>>(
      enc_p, WT_v, b_v, attv_b, nullptr, nullptr, B_ * L_, 512, 512, 512, 0);

  // ---- persistent 25-step scan ----
  scan_fused<<<dim3(NBLK), dim3(256), 0, stream>>>(
      A1, WT_g, bgx, cbuf, sbuf, Aag, projA, WT_a, bax, agswb,
      attv_b, w_a, enc_r, clen, alphas, betas, bar);

  // proj = x + [h|ctx] @ [W_Lh;W_Lz] + b   (3200 x 512 x 1024, packed out)
  gemm_pk<4, 2, EPI_PROJ><<<dim3(50, 4), dim3(256), 0, stream>>>(
      projA, WT_p, bpx, projb, (const bf16*)A1, nullptr, T_ * 128, 512, 1024, 0, 0);
  // preds = proj @ W_Lo + b_Lo  (3200 x 10000 x 512)
  gemm_pk<4, 4, EPI_OUT><<<dim3(50, 40), dim3(256), 0, stream>>>(
      projb, WT_lo, b_Lo, preds, nullptr, nullptr, T_ * 128, V_, 512, 0, 0);
}

// Round 6
// 1458.217 us; speedup vs baseline: 1.5784x; 1.2481x over previous
//
#include <hip/hip_runtime.h>
#include <hip/hip_bf16.h>
#include <cstdint>
#include <cstddef>

using bf16 = __hip_bfloat16;
typedef __attribute__((ext_vector_type(4))) float f32x4;
typedef __attribute__((ext_vector_type(8))) short bf16x8;

#define B_ 128
#define L_ 196
#define T_ 25
#define V_ 10000
#define NBLK 256

__device__ __forceinline__ float b2f(short s) {
  unsigned u = ((unsigned)(unsigned short)s) << 16;
  return __uint_as_float(u);
}
__device__ __forceinline__ bf16 f2b(float f) { return __float2bfloat16(f); }
__device__ __forceinline__ short f2bs(float f) {
  return __builtin_bit_cast(short, __float2bfloat16(f));
}
__device__ __forceinline__ float sigf(float x) { return 1.f / (1.f + __expf(-x)); }
__device__ __forceinline__ float tanh_fast(float x) { return 1.f - 2.f / (1.f + __expf(2.f * x)); }

// sc1 write-through stores (push to L3, cross-XCD visible after vmcnt drain).
// Readers use NORMAL cached loads on per-step never-before-touched slots.
__device__ __forceinline__ void cst_u32(unsigned* p, unsigned v) {
  __hip_atomic_store(p, v, __ATOMIC_RELAXED, __HIP_MEMORY_SCOPE_AGENT);
}
__device__ __forceinline__ unsigned cld_u32(const unsigned* p) {
  return __hip_atomic_load((unsigned*)p, __ATOMIC_RELAXED, __HIP_MEMORY_SCOPE_AGENT);
}
__device__ __forceinline__ void cst_f32(float* p, float v) {
  __hip_atomic_store(p, v, __ATOMIC_RELAXED, __HIP_MEMORY_SCOPE_AGENT);
}

// Fragment-packed layout: 16x32 tiles, tile-row-major; element (r,c) at
// (((r>>4)*KT + (c>>5))*64 + ((c&31)>>3)*16 + (r&15))*8 + (c&7).
__device__ __forceinline__ size_t pidx(int row, int col, int K) {
  int KT = K >> 5;
  return (((size_t)(row >> 4) * KT + (col >> 5)) * 64 +
          (size_t)(((col & 31) >> 3) * 16 + (row & 15))) * 8 + (col & 7);
}

__device__ __forceinline__ float wred_sum(float x) {
#pragma unroll
  for (int off = 32; off >= 1; off >>= 1) x += __shfl_xor(x, off, 64);
  return x;
}
__device__ __forceinline__ float wred_max(float x) {
#pragma unroll
  for (int off = 32; off >= 1; off >>= 1) x = fmaxf(x, __shfl_xor(x, off, 64));
  return x;
}

// ---- two-level grid barrier: relaxed atomics only ----
__device__ __forceinline__ void gbar(unsigned* bs) {
  __syncthreads();               // per-wave vmcnt(0) drain before joining
  if (threadIdx.x == 0) {
    asm volatile("s_waitcnt vmcnt(0)" ::: "memory");
    unsigned* lcnt = bs;         // 16 shards, 128B apart
    unsigned* cnt  = bs + 512;
    unsigned* gen  = bs + 544;
    unsigned g = cld_u32(gen);
    int grp = (int)(blockIdx.x & 15u);
    unsigned a = __hip_atomic_fetch_add(&lcnt[grp * 32], 1u, __ATOMIC_RELAXED,
                                        __HIP_MEMORY_SCOPE_AGENT);
    bool rel = false;
    if ((a & 15u) == 15u) {
      unsigned b = __hip_atomic_fetch_add(cnt, 1u, __ATOMIC_RELAXED,
                                          __HIP_MEMORY_SCOPE_AGENT);
      if ((b & 15u) == 15u) {
        cst_u32(gen, g + 1u);
        rel = true;
      }
    }
    if (!rel) {
      while (cld_u32(gen) == g) __builtin_amdgcn_s_sleep(1);
    }
  }
  __syncthreads();
}

// ---- persistent scan kernel: 25 steps, 2 grid barriers per step ----
__global__ __launch_bounds__(256) void scan_fused(
    bf16* __restrict__ A1,          // (T_+1) x (128x1024 packed): [x | h]
    const bf16* __restrict__ WT_g,  // 2560x1024 packed
    const float* __restrict__ bgx,
    float* __restrict__ cbuf,       // 128x512 f32 (block-private)
    bf16* __restrict__ Aag,         // T_ x 128x1024 packed [h|s]  (per-step slots)
    bf16* __restrict__ projA,       // T_ x (128x1024 packed): [h | ctx]
    const bf16* __restrict__ WT_a,  // 1024x1024 packed
    const float* __restrict__ bax,
    float* __restrict__ agswb,      // T_ x 128x1024 f32 (per-step slots)
    const bf16* __restrict__ attv,  // 25088x512 row-major bf16
    const float* __restrict__ w_a,
    const int* __restrict__ clen,
    float* __restrict__ alphas, float* __restrict__ betas,
    float* __restrict__ alphas_raw, float* __restrict__ betas_raw,
    unsigned* __restrict__ bar)
{
  const int blk = blockIdx.x;
  const int tid = threadIdx.x;
  const int wv = tid >> 6, lane = tid & 63;
  const int r16 = lane & 15, kg = lane >> 4;
  __shared__ f32x4 pacc[4][10][64];   // 40 KB split-K partials
  __shared__ float sh[200];
  __shared__ float red[8];

  for (int tt = 0; tt <= T_; ++tt) {
    if (blk >= 128) {
      // ---- P1: gates GEMM (t=tt) + fused LSTM pointwise; 4 waves split kt ----
      if (tt < T_) {
        int job = blk - 128;
        int mi = job >> 5;              // 0..3 (32-row group)
        int di = job & 31;              // 0..31 (16-col d group)
        const bf16* A1t = A1 + (size_t)tt * 131072;
        f32x4 acc[2][5];
#pragma unroll
        for (int i = 0; i < 2; i++)
#pragma unroll
          for (int g = 0; g < 5; g++) acc[i][g] = f32x4{0.f, 0.f, 0.f, 0.f};
        const bf16* ap0 = A1t + (size_t)(mi * 2 + 0) * 16384 + lane * 8;
        const bf16* ap1 = A1t + (size_t)(mi * 2 + 1) * 16384 + lane * 8;
        const bf16* bp0 = WT_g + (size_t)(0 * 32 + di) * 16384 + lane * 8;
        const bf16* bp1 = WT_g + (size_t)(1 * 32 + di) * 16384 + lane * 8;
        const bf16* bp2 = WT_g + (size_t)(2 * 32 + di) * 16384 + lane * 8;
        const bf16* bp3 = WT_g + (size_t)(3 * 32 + di) * 16384 + lane * 8;
        const bf16* bp4 = WT_g + (size_t)(4 * 32 + di) * 16384 + lane * 8;
        // wave wv covers kt = wv*8 .. wv*8+7 (normal cached loads everywhere;
        // h-half slots are per-step and never cached before their write)
#pragma unroll 4
        for (int kk = 0; kk < 8; kk++) {
          size_t o = (size_t)(wv * 8 + kk) * 512;
          bf16x8 a0 = *(const bf16x8*)(const void*)(ap0 + o);
          bf16x8 a1 = *(const bf16x8*)(const void*)(ap1 + o);
          bf16x8 b0 = *(const bf16x8*)(const void*)(bp0 + o);
          bf16x8 b1 = *(const bf16x8*)(const void*)(bp1 + o);
          bf16x8 b2 = *(const bf16x8*)(const void*)(bp2 + o);
          bf16x8 b3 = *(const bf16x8*)(const void*)(bp3 + o);
          bf16x8 b4 = *(const bf16x8*)(const void*)(bp4 + o);
          acc[0][0] = __builtin_amdgcn_mfma_f32_16x16x32_bf16(a0, b0, acc[0][0], 0, 0, 0);
          acc[1][0] = __builtin_amdgcn_mfma_f32_16x16x32_bf16(a1, b0, acc[1][0], 0, 0, 0);
          acc[0][1] = __builtin_amdgcn_mfma_f32_16x16x32_bf16(a0, b1, acc[0][1], 0, 0, 0);
          acc[1][1] = __builtin_amdgcn_mfma_f32_16x16x32_bf16(a1, b1, acc[1][1], 0, 0, 0);
          acc[0][2] = __builtin_amdgcn_mfma_f32_16x16x32_bf16(a0, b2, acc[0][2], 0, 0, 0);
          acc[1][2] = __builtin_amdgcn_mfma_f32_16x16x32_bf16(a1, b2, acc[1][2], 0, 0, 0);
          acc[0][3] = __builtin_amdgcn_mfma_f32_16x16x32_bf16(a0, b3, acc[0][3], 0, 0, 0);
          acc[1][3] = __builtin_amdgcn_mfma_f32_16x16x32_bf16(a1, b3, acc[1][3], 0, 0, 0);
          acc[0][4] = __builtin_amdgcn_mfma_f32_16x16x32_bf16(a0, b4, acc[0][4], 0, 0, 0);
          acc[1][4] = __builtin_amdgcn_mfma_f32_16x16x32_bf16(a1, b4, acc[1][4], 0, 0, 0);
        }
#pragma unroll
        for (int i = 0; i < 2; i++)
#pragma unroll
          for (int g = 0; g < 5; g++) pacc[wv][i * 5 + g][lane] = acc[i][g];
        __syncthreads();
        if (wv == 0) {
          int d = di * 16 + r16;
          float bi0 = bgx[d], bi1 = bgx[512 + d], bi2 = bgx[1024 + d];
          float bi3 = bgx[1536 + d], bi4 = bgx[2048 + d];
          bf16* hnext = A1 + (size_t)(tt + 1) * 131072;
          bf16* pA = projA + (size_t)tt * 131072;
          bf16* AagT = Aag + (size_t)tt * 131072;
#pragma unroll
          for (int i = 0; i < 2; i++) {
            f32x4 g0 = pacc[0][i * 5 + 0][lane] + pacc[1][i * 5 + 0][lane] +
                       pacc[2][i * 5 + 0][lane] + pacc[3][i * 5 + 0][lane];
            f32x4 g1 = pacc[0][i * 5 + 1][lane] + pacc[1][i * 5 + 1][lane] +
                       pacc[2][i * 5 + 1][lane] + pacc[3][i * 5 + 1][lane];
            f32x4 g2 = pacc[0][i * 5 + 2][lane] + pacc[1][i * 5 + 2][lane] +
                       pacc[2][i * 5 + 2][lane] + pacc[3][i * 5 + 2][lane];
            f32x4 g3 = pacc[0][i * 5 + 3][lane] + pacc[1][i * 5 + 3][lane] +
                       pacc[2][i * 5 + 3][lane] + pacc[3][i * 5 + 3][lane];
            f32x4 g4 = pacc[0][i * 5 + 4][lane] + pacc[1][i * 5 + 4][lane] +
                       pacc[2][i * 5 + 4][lane] + pacc[3][i * 5 + 4][lane];
#pragma unroll
            for (int r = 0; r < 4; r++) {
              int m = mi * 32 + i * 16 + kg * 4 + r;
              float cn = sigf(g1[r] + bi1) * cbuf[m * 512 + d] +
                         sigf(g0[r] + bi0) * tanh_fast(g2[r] + bi2);
              float tcn = tanh_fast(cn);
              float hn = sigf(g3[r] + bi3) * tcn;
              float ss = sigf(g4[r] + bi4) * tcn;
              cbuf[m * 512 + d] = cn;
              size_t plo = pidx(m, d, 1024), phi = pidx(m, 512 + d, 1024);
              pA[plo] = f2b(hn);                      // tail-kernel consumer
              float hn1 = __shfl_down(hn, 1);
              float ss1 = __shfl_down(ss, 1);
              if (!(r16 & 1)) {
                unsigned hp = (unsigned)(unsigned short)f2bs(hn) |
                              ((unsigned)(unsigned short)f2bs(hn1) << 16);
                unsigned sp = (unsigned)(unsigned short)f2bs(ss) |
                              ((unsigned)(unsigned short)f2bs(ss1) << 16);
                cst_u32((unsigned*)(void*)(AagT + plo), hp);
                cst_u32((unsigned*)(void*)(AagT + phi), sp);
                cst_u32((unsigned*)(void*)(hnext + phi), hp);
              }
            }
          }
        }
      }
    } else {
      // ---- P4: e-scores + softmax for t = tt-1; one block per batch elem ----
      if (tt >= 1) {
        int t = tt - 1, b = blk;
        const float* ag = agswb + (size_t)t * 131072 + b * 1024;  // per-step slot
        int a0 = lane * 8;
        float ag8[8], wa8[8], sw8[8];
#pragma unroll
        for (int j = 0; j < 8; j++) {
          ag8[j] = ag[a0 + j];
          wa8[j] = w_a[a0 + j];
          sw8[j] = ag[512 + a0 + j];
        }
        // 4-row-batched e-pass for MLP
        for (int base = wv; base < 197; base += 16) {
          bf16x8 av[4];
#pragma unroll
          for (int q = 0; q < 4; q++) {
            int l = base + 4 * q;
            if (l < 196)
              av[q] = *(const bf16x8*)(const void*)(attv + ((size_t)(b * 196 + l)) * 512 + a0);
          }
#pragma unroll
          for (int q = 0; q < 4; q++) {
            int l = base + 4 * q;
            if (l > 196) continue;    // wave-uniform
            float part = 0.f;
            if (l < 196) {
#pragma unroll
              for (int j = 0; j < 8; j++) part += wa8[j] * tanh_fast(b2f(av[q][j]) + ag8[j]);
            } else {
#pragma unroll
              for (int j = 0; j < 8; j++) part += wa8[j] * tanh_fast(sw8[j] + ag8[j]);
            }
            part = wred_sum(part);
            if (lane == 0) sh[l] = part;
          }
        }
        __syncthreads();
        float v = (tid < 197) ? sh[tid] : -1e30f;
        float mx = wred_max(v);
        if (lane == 0) red[wv] = mx;
        __syncthreads();
        mx = fmaxf(fmaxf(red[0], red[1]), fmaxf(red[2], red[3]));
        float p = (tid < 197) ? __expf(v - mx) : 0.f;
        float sm = wred_sum(p);
        if (lane == 0) red[4 + wv] = sm;
        __syncthreads();
        float inv = 1.f / (red[4] + red[5] + red[6] + red[7]);
        float a = p * inv;
        int dec = clen[b] - 1; if (dec < 1) dec = 1;
        float act = (t < dec) ? 1.f : 0.f;
        if (tid < 196) {
          alphas[(size_t)b * (T_ * L_) + (size_t)t * L_ + tid] = a * act;
          alphas_raw[(size_t)b * (T_ * L_) + (size_t)t * L_ + tid] = a;
        }
        if (tid == 196) {
          betas[b * T_ + t] = a * act;
          betas_raw[b * T_ + t] = a;
        }
      }
    }
    if (tt < T_) {
      gbar(bar);
      // ---- P3: agsw(tt) = [h|s] @ WT_a^T + bax; waves 0-1 of every block ----
      if (wv < 2) {
        int job = blk * 2 + wv;   // 0..511
        int mi = job >> 6;        // 0..7
        int ni = job & 63;        // 0..63
        f32x4 a3 = f32x4{0.f, 0.f, 0.f, 0.f};
        const bf16* AagT = Aag + (size_t)tt * 131072;
        float* agw = agswb + (size_t)tt * 131072;
        const bf16* ap = AagT + (size_t)mi * 16384 + lane * 8;
        const bf16* bp = WT_a + (size_t)ni * 16384 + lane * 8;
#pragma unroll 4
        for (int kt = 0; kt < 32; kt++) {
          bf16x8 af = *(const bf16x8*)(const void*)(ap + (size_t)kt * 512);
          bf16x8 bf_ = *(const bf16x8*)(const void*)(bp + (size_t)kt * 512);
          a3 = __builtin_amdgcn_mfma_f32_16x16x32_bf16(af, bf_, a3, 0, 0, 0);
        }
        int n = ni * 16 + r16;
#pragma unroll
        for (int r = 0; r < 4; r++) {
          int m = mi * 16 + kg * 4 + r;
          cst_f32(&agw[m * 1024 + n], a3[r] + bax[n]);
        }
      }
      gbar(bar);
    }
  }
}

// ---- tail: ctx(b,t,:) = alpha_raw(b,t,:) @ enc(b) + beta*s ; write projA ctx ----
__global__ __launch_bounds__(256) void ctx_tail(
    const float* __restrict__ alphas_raw, const float* __restrict__ betas_raw,
    const bf16* __restrict__ enc_r, const bf16* __restrict__ Aag,
    bf16* __restrict__ projA)
{
  int b = blockIdx.x, cs = blockIdx.y, tid = threadIdx.x;
  __shared__ float al[T_ * 200];
  for (int i = tid; i < T_ * 196; i += 256) {
    al[(i / 196) * 200 + (i % 196)] = alphas_raw[(size_t)b * (T_ * 196) + i];
  }
  __syncthreads();
  int ch = cs * 256 + tid;
  float acc[T_];
#pragma unroll
  for (int t = 0; t < T_; t++) acc[t] = 0.f;
  const short* ep = (const short*)(const void*)(enc_r) + (size_t)b * 196 * 512 + ch;
#pragma unroll 4
  for (int l = 0; l < 196; l++) {
    float e = b2f(ep[(size_t)l * 512]);
#pragma unroll
    for (int t = 0; t < T_; t++) acc[t] += al[t * 200 + l] * e;
  }
#pragma unroll
  for (int t = 0; t < T_; t++) {
    float beta = betas_raw[b * T_ + t];
    float sv = b2f(((const short*)(const void*)Aag)[(size_t)t * 131072 + pidx(b, 512 + ch, 1024)]);
    projA[(size_t)t * 131072 + pidx(b, 512 + ch, 1024)] = f2b(acc[t] + beta * sv);
  }
}

enum { EPI_F32 = 0, EPI_BF16 = 1, EPI_INIT = 2, EPI_PROJ = 3, EPI_OUT = 4 };

// C = A (MxK packed) @ BT^T (BT: NxK packed), + bias.
template<int MFRAG, int NFRAG, int EPI>
__global__ __launch_bounds__(256) void gemm_pk(
    const bf16* __restrict__ A, const bf16* __restrict__ BT,
    const float* __restrict__ bias, void* __restrict__ Cp,
    const bf16* __restrict__ auxA, float* __restrict__ auxB,
    int M, int N, int K, int ldc, int R0)
{
  const int lane = threadIdx.x & 63;
  const int wv = threadIdx.x >> 6;
  const int r16 = lane & 15;
  const int kg = lane >> 4;
  const int m0 = blockIdx.x * (MFRAG * 16);
  const int n0 = blockIdx.y * (NFRAG * 64) + wv * (NFRAG * 16);
  const int KT = K >> 5;

  f32x4 acc[MFRAG][NFRAG];
#pragma unroll
  for (int i = 0; i < MFRAG; i++)
#pragma unroll
    for (int j = 0; j < NFRAG; j++) acc[i][j] = f32x4{0.f, 0.f, 0.f, 0.f};

  const bf16* ap = A + (size_t)(m0 >> 4) * KT * 512 + lane * 8;
  const bf16* bp = BT + (size_t)(n0 >> 4) * KT * 512 + lane * 8;

#pragma unroll 4
  for (int kt = 0; kt < KT; kt++) {
    bf16x8 af[MFRAG], bfr[NFRAG];
#pragma unroll
    for (int i = 0; i < MFRAG; i++)
      af[i] = *(const bf16x8*)(const void*)(ap + ((size_t)i * KT + kt) * 512);
#pragma unroll
    for (int j = 0; j < NFRAG; j++)
      bfr[j] = *(const bf16x8*)(const void*)(bp + ((size_t)j * KT + kt) * 512);
#pragma unroll
    for (int i = 0; i < MFRAG; i++)
#pragma unroll
      for (int j = 0; j < NFRAG; j++)
        acc[i][j] = __builtin_amdgcn_mfma_f32_16x16x32_bf16(af[i], bfr[j], acc[i][j], 0, 0, 0);
  }

#pragma unroll
  for (int i = 0; i < MFRAG; i++)
#pragma unroll
    for (int j = 0; j < NFRAG; j++)
#pragma unroll
      for (int r = 0; r < 4; r++) {
        int m = m0 + i * 16 + kg * 4 + r;
        int n = n0 + j * 16 + r16;
        if (n >= N) continue;
        float v = acc[i][j][r] + bias[n];
        if constexpr (EPI == EPI_F32) {
          ((float*)Cp)[(size_t)m * ldc + n] = v;
        } else if constexpr (EPI == EPI_BF16) {
          ((bf16*)Cp)[(size_t)m * ldc + n] = f2b(v);
        } else if constexpr (EPI == EPI_INIT) {
          float tv = tanhf(v);
          if (n < 512) ((bf16*)Cp)[pidx(m, 512 + n, 1024)] = f2b(tv);  // h0 -> A1[0]
          else auxB[(size_t)m * 512 + (n - 512)] = tv;                 // c0 (f32)
        } else if constexpr (EPI == EPI_PROJ) {
          int t = m >> 7, b = m & 127;
          v += b2f(((const short*)auxA)[(size_t)t * 131072 + pidx(b, n, 1024)]);  // + x
          ((bf16*)Cp)[pidx(m, n, 512)] = f2b(v);
        } else {  // EPI_OUT: preds[b, t, n], row = t*128+b
          int t = m >> 7, b = m & 127;
          ((float*)Cp)[(size_t)b * (T_ * V_) + (size_t)t * V_ + n] = v;
        }
      }
}

// Packed-transpose: dst (nrows x K packed) = [top; bot]^T with zero padding.
__global__ void trans_pack(const float* __restrict__ top, const float* __restrict__ bot,
                           bf16* __restrict__ dst, int ncols, long nElem8, int ktop, int K)
{
  int KT = K >> 5;
  for (long t8 = (long)blockIdx.x * blockDim.x + threadIdx.x; t8 < nElem8;
       t8 += (long)gridDim.x * blockDim.x) {
    int r = (int)(t8 & 15);
    int kg = (int)((t8 >> 4) & 3);
    long tile = t8 >> 6;
    int kt = (int)(tile % KT);
    int rt = (int)(tile / KT);
    int n = rt * 16 + r;
    int kb = kt * 32 + kg * 8;
    bf16x8 out;
#pragma unroll
    for (int j = 0; j < 8; j++) {
      int k = kb + j;
      float v = 0.f;
      if (n < ncols) {
        if (k < ktop) { if (top) v = top[(size_t)k * ncols + n]; }
        else if (bot) { v = bot[(size_t)(k - ktop) * ncols + n]; }
      }
      out[j] = f2bs(v);
    }
    *(bf16x8*)(void*)(dst + t8 * 8) = out;
  }
}

// enc (f32 row-major) -> enc_p (bf16 packed) AND enc_r (bf16 row-major)
__global__ void conv_pack(const float* __restrict__ src, bf16* __restrict__ dst,
                          bf16* __restrict__ dst_row, long nElem8)
{
  for (long t8 = (long)blockIdx.x * blockDim.x + threadIdx.x; t8 < nElem8;
       t8 += (long)gridDim.x * blockDim.x) {
    int r = (int)(t8 & 15);
    int kg = (int)((t8 >> 4) & 3);
    long tile = t8 >> 6;
    int kt = (int)(tile & 15);           // KT = 16 (K=512)
    int rt = (int)(tile >> 4);
    size_t rowoff = ((size_t)(rt * 16 + r)) * 512 + kt * 32 + kg * 8;
    const float* s = src + rowoff;
    bf16x8 out;
#pragma unroll
    for (int j = 0; j < 8; j++) out[j] = f2bs(s[j]);
    *(bf16x8*)(void*)(dst + t8 * 8) = out;
    *(bf16x8*)(void*)(dst_row + rowoff) = out;
  }
}

__global__ void bias_comb(const float* __restrict__ b_lstm, const float* __restrict__ b_s,
                          const float* __restrict__ b_g, const float* __restrict__ b_sa,
                          const float* __restrict__ b_Lh, const float* __restrict__ b_Lz,
                          const float* __restrict__ b_ih, const float* __restrict__ b_ic,
                          float* __restrict__ bg, float* __restrict__ ba,
                          float* __restrict__ bp, float* __restrict__ bi)
{
  int i = blockIdx.x * blockDim.x + threadIdx.x;
  if (i < 2560) bg[i] = (i < 2048) ? b_lstm[i] : b_s[i - 2048];
  if (i < 1024) ba[i] = (i < 512) ? b_g[i] : b_sa[i - 512];
  if (i < 512)  bp[i] = b_Lh[i] + b_Lz[i];
  if (i < 1024) bi[i] = (i < 512) ? b_ih[i] : b_ic[i - 512];
}

__global__ __launch_bounds__(128) void mean_enc(const float* __restrict__ enc,
                                                bf16* __restrict__ mb)
{
  int b = blockIdx.x, c = blockIdx.y * 128 + threadIdx.x;
  float s = 0.f;
  for (int l = 0; l < L_; l++) s += enc[((size_t)b * L_ + l) * 512 + c];
  mb[pidx(b, c, 512)] = f2b(s * (1.f / (float)L_));
}

__global__ void gather_x(const float* __restrict__ emb, const int* __restrict__ caps,
                         bf16* __restrict__ A1)
{
  int tb = blockIdx.x;          // t*128 + b
  int t = tb >> 7, b = tb & 127;
  int word = caps[b * 26 + t];
  int c0 = threadIdx.x * 8;
  const float* src = emb + (size_t)word * 512 + c0;
  bf16* dst = A1 + (size_t)t * (128 * 1024) + pidx(b, c0, 1024);
  bf16x8 out;
#pragma unroll
  for (int j = 0; j < 8; j++) out[j] = f2bs(src[j]);
  *(bf16x8*)(void*)dst = out;
}

extern "C" void kernel_launch(void* const* d_in, const int* in_sizes, int n_in,
                              void* d_out, int out_size, void* d_ws, size_t ws_size,
                              hipStream_t stream)
{
  const float* enc      = (const float*)d_in[0];
  const int*   caps     = (const int*)d_in[1];
  const int*   clen     = (const int*)d_in[2];
  const float* emb      = (const float*)d_in[3];
  const float* W_ih     = (const float*)d_in[4];
  const float* W_hh     = (const float*)d_in[5];
  const float* b_lstm   = (const float*)d_in[6];
  const float* Wx_s     = (const float*)d_in[7];
  const float* Wh_s     = (const float*)d_in[8];
  const float* b_s      = (const float*)d_in[9];
  const float* W_v      = (const float*)d_in[10];
  const float* b_v      = (const float*)d_in[11];
  const float* W_g      = (const float*)d_in[12];
  const float* b_g      = (const float*)d_in[13];
  const float* W_s_att  = (const float*)d_in[14];
  const float* b_sa     = (const float*)d_in[15];
  const float* w_a      = (const float*)d_in[16];
  const float* W_init_h = (const float*)d_in[17];
  const float* b_init_h = (const float*)d_in[18];
  const float* W_init_c = (const float*)d_in[19];
  const float* b_init_c = (const float*)d_in[20];
  const float* W_Lh     = (const float*)d_in[21];
  const float* b_Lh     = (const float*)d_in[22];
  const float* W_Lz     = (const float*)d_in[23];
  const float* b_Lz     = (const float*)d_in[24];
  const float* W_Lo     = (const float*)d_in[25];
  const float* b_Lo     = (const float*)d_in[26];

  float* preds  = (float*)d_out;
  float* alphas = preds + (size_t)B_ * T_ * V_;
  float* betas  = alphas + (size_t)B_ * T_ * L_;

  char* ws = (char*)d_ws;
  size_t off = 0;
  auto alloc = [&](size_t bytes) -> void* {
    void* p = ws + off;
    off = (off + bytes + 255) & ~(size_t)255;
    return p;
  };
  bf16*  enc_p  = (bf16*)alloc((size_t)B_ * L_ * 512 * 2);   // dead after att_v GEMM
  bf16*  enc_r  = (bf16*)alloc((size_t)B_ * L_ * 512 * 2);
  bf16*  attv_b = (bf16*)alloc((size_t)B_ * L_ * 512 * 2);
  bf16*  WT_g   = (bf16*)alloc((size_t)2560 * 1024 * 2);
  bf16*  WT_a   = (bf16*)alloc((size_t)1024 * 1024 * 2);
  bf16*  WT_p   = (bf16*)alloc((size_t)512 * 1024 * 2);
  bf16*  WT_lo  = (bf16*)alloc((size_t)10240 * 512 * 2);
  bf16*  WT_v   = (bf16*)alloc((size_t)512 * 512 * 2);
  bf16*  WT_i   = (bf16*)alloc((size_t)1024 * 512 * 2);
  float* bgx    = (float*)alloc(2560 * 4);
  float* bax    = (float*)alloc(1024 * 4);
  float* bpx    = (float*)alloc(512 * 4);
  float* bix    = (float*)alloc(1024 * 4);
  bf16*  mean_b = (bf16*)alloc(128 * 512 * 2);
  bf16*  A1     = (bf16*)alloc((size_t)(T_ + 1) * 128 * 1024 * 2);
  bf16*  projA  = (bf16*)alloc((size_t)T_ * 128 * 1024 * 2);
  bf16*  projb  = (bf16*)alloc((size_t)T_ * 128 * 512 * 2);
  float* cbuf   = (float*)alloc(128 * 512 * 4);
  unsigned* bar = (unsigned*)alloc(4096);
  if (off > ws_size) return;  // loud validation failure if ws too small

  // Overlay scan-time buffers onto dead enc_p (25,690,112 B):
  //   agswb 13,107,200 | Aag 6,553,600 | alphas_raw 2,508,800 | betas_raw 12,800
  float* agswb      = (float*)enc_p;
  bf16*  Aag        = (bf16*)((char*)enc_p + 13107200);
  float* alphas_raw = (float*)((char*)enc_p + 19660800);
  float* betas_raw  = (float*)((char*)enc_p + 22169600);

  hipMemsetAsync(bar, 0, 4096, stream);

  // ---- prep ----
  bias_comb<<<dim3(10), dim3(256), 0, stream>>>(b_lstm, b_s, b_g, b_sa, b_Lh, b_Lz,
                                                b_init_h, b_init_c, bgx, bax, bpx, bix);
  auto TP = [&](const float* top, const float* bot, bf16* dst, int ncols, int nrows,
                int ktop, int K) {
    long n8 = (long)nrows * K / 8;
    int blocks = (int)((n8 + 255) / 256);
    if (blocks > 4096) blocks = 4096;
    trans_pack<<<dim3(blocks), dim3(256), 0, stream>>>(top, bot, dst, ncols, n8, ktop, K);
  };
  TP(W_ih, W_hh, WT_g, 2048, 2048, 512, 1024);
  TP(Wx_s, Wh_s, WT_g + (size_t)2048 * 1024, 512, 512, 512, 1024);
  TP(W_Lh, W_Lz, WT_p, 512, 512, 512, 1024);
  TP(W_g, nullptr, WT_a, 512, 512, 512, 1024);
  TP(nullptr, W_s_att, WT_a + (size_t)512 * 1024, 512, 512, 512, 1024);
  TP(W_Lo, nullptr, WT_lo, 10000, 10240, 512, 512);
  TP(W_v, nullptr, WT_v, 512, 512, 512, 512);
  TP(W_init_h, nullptr, WT_i, 512, 512, 512, 512);
  TP(W_init_c, nullptr, WT_i + (size_t)512 * 512, 512, 512, 512, 512);
  conv_pack<<<dim3(4096), dim3(256), 0, stream>>>(enc, enc_p, enc_r,
                                                  (long)B_ * L_ * 512 / 8);
  mean_enc<<<dim3(128, 4), dim3(128), 0, stream>>>(enc, mean_b);
  gather_x<<<dim3(T_ * 128), dim3(64), 0, stream>>>(emb, caps, A1);

  // h0 -> A1[0] h-slot (packed bf16), c0 -> cbuf (f32)
  gemm_pk<1, 1, EPI_INIT><<<dim3(8, 16), dim3(256), 0, stream>>>(
      mean_b, WT_i, bix, (void*)A1, nullptr, cbuf, 128, 1024, 512, 0, 0);
  // att_v = enc @ W_v + b_v   (bf16 row-major out) — last consumer of enc_p
  gemm_pk<4, 2, EPI_BF16><<<dim3(392, 4), dim3(256), 0, stream>>>(
      enc_p, WT_v, b_v, attv_b, nullptr, nullptr, B_ * L_, 512, 512, 512, 0);

  // ---- persistent 25-step scan ----
  scan_fused<<<dim3(NBLK), dim3(256), 0, stream>>>(
      A1, WT_g, bgx, cbuf, Aag, projA, WT_a, bax, agswb,
      attv_b, w_a, clen, alphas, betas, alphas_raw, betas_raw, bar);

  // ctx -> projA ctx-slots (reads enc ONCE, batched over all t)
  ctx_tail<<<dim3(128, 2), dim3(256), 0, stream>>>(alphas_raw, betas_raw, enc_r,
                                                   Aag, projA);

  // proj = x + [h|ctx] @ [W_Lh;W_Lz] + b   (3200 x 512 x 1024, packed out)
  gemm_pk<4, 2, EPI_PROJ><<<dim3(50, 4), dim3(256), 0, stream>>>(
      projA, WT_p, bpx, projb, (const bf16*)A1, nullptr, T_ * 128, 512, 1024, 0, 0);
  // preds = proj @ W_Lo + b_Lo  (3200 x 10000 x 512)
  gemm_pk<4, 4, EPI_OUT><<<dim3(50, 40), dim3(256), 0, stream>>>(
      projb, WT_lo, b_Lo, preds, nullptr, nullptr, T_ * 128, V_, 512, 0, 0);
}

// Round 7
// 628.960 us; speedup vs baseline: 3.6593x; 2.3185x over previous
//
#include <hip/hip_runtime.h>
#include <hip/hip_bf16.h>
#include <cstdint>
#include <cstddef>

using bf16 = __hip_bfloat16;
typedef __attribute__((ext_vector_type(4))) float f32x4;
typedef __attribute__((ext_vector_type(8))) short bf16x8;

#define B_ 128
#define L_ 196
#define T_ 25
#define V_ 10000
#define NBLK 256

__device__ __forceinline__ float b2f(short s) {
  unsigned u = ((unsigned)(unsigned short)s) << 16;
  return __uint_as_float(u);
}
__device__ __forceinline__ bf16 f2b(float f) { return __float2bfloat16(f); }
__device__ __forceinline__ short f2bs(float f) {
  return __builtin_bit_cast(short, __float2bfloat16(f));
}
__device__ __forceinline__ float sigf(float x) { return 1.f / (1.f + __expf(-x)); }
__device__ __forceinline__ float tanh_fast(float x) { return 1.f - 2.f / (1.f + __expf(2.f * x)); }

// sc1 write-through stores (push to L3, cross-XCD visible after vmcnt drain).
// Readers use NORMAL cached loads on addresses never touched earlier in the
// dispatch (cold miss -> L3 -> pushed data). Validated R6.
__device__ __forceinline__ void cst_u32(unsigned* p, unsigned v) {
  __hip_atomic_store(p, v, __ATOMIC_RELAXED, __HIP_MEMORY_SCOPE_AGENT);
}
__device__ __forceinline__ unsigned cld_u32(const unsigned* p) {
  return __hip_atomic_load((unsigned*)p, __ATOMIC_RELAXED, __HIP_MEMORY_SCOPE_AGENT);
}

// Fragment-packed layout: 16x32 tiles, tile-row-major; element (r,c) at
// (((r>>4)*KT + (c>>5))*64 + ((c&31)>>3)*16 + (r&15))*8 + (c&7).
__device__ __forceinline__ size_t pidx(int row, int col, int K) {
  int KT = K >> 5;
  return (((size_t)(row >> 4) * KT + (col >> 5)) * 64 +
          (size_t)(((col & 31) >> 3) * 16 + (row & 15))) * 8 + (col & 7);
}

__device__ __forceinline__ float wred_sum(float x) {
#pragma unroll
  for (int off = 32; off >= 1; off >>= 1) x += __shfl_xor(x, off, 64);
  return x;
}
__device__ __forceinline__ float wred_max(float x) {
#pragma unroll
  for (int off = 32; off >= 1; off >>= 1) x = fmaxf(x, __shfl_xor(x, off, 64));
  return x;
}

// ---- two-level grid barrier: relaxed atomics only ----
__device__ __forceinline__ void gbar(unsigned* bs) {
  __syncthreads();
  if (threadIdx.x == 0) {
    asm volatile("s_waitcnt vmcnt(0)" ::: "memory");
    unsigned* lcnt = bs;         // 16 shards, 128B apart
    unsigned* cnt  = bs + 512;
    unsigned* gen  = bs + 544;
    unsigned g = cld_u32(gen);
    int grp = (int)(blockIdx.x & 15u);
    unsigned a = __hip_atomic_fetch_add(&lcnt[grp * 32], 1u, __ATOMIC_RELAXED,
                                        __HIP_MEMORY_SCOPE_AGENT);
    bool rel = false;
    if ((a & 15u) == 15u) {
      unsigned b = __hip_atomic_fetch_add(cnt, 1u, __ATOMIC_RELAXED,
                                          __HIP_MEMORY_SCOPE_AGENT);
      if ((b & 15u) == 15u) {
        cst_u32(gen, g + 1u);
        rel = true;
      }
    }
    if (!rel) {
      while (cld_u32(gen) == g) __builtin_amdgcn_s_sleep(1);
    }
  }
  __syncthreads();
}

// ---- persistent scan: ONLY the LSTM recurrence; 1 barrier per step ----
// 256 blocks = 8 mi (16-row tiles) x 32 di (16-d tiles). Waves split K 4-way.
__global__ __launch_bounds__(256) void scan26(
    bf16* __restrict__ A1,          // (T_+1) x (128x1024 packed): [x | h]
    const bf16* __restrict__ WT_g,  // 2560x1024 packed
    const float* __restrict__ bgx,  // 2560 combined bias
    float* __restrict__ cbuf,       // 128x512 f32 (block-private tiles)
    bf16* __restrict__ Aag,         // T_ x 128x1024 packed [h|s]  (post-scan)
    bf16* __restrict__ projA,       // T_ x 128x1024 packed [h|ctx] (post-scan)
    unsigned* __restrict__ bar)
{
  const int blk = blockIdx.x;
  const int tid = threadIdx.x;
  const int wv = tid >> 6, lane = tid & 63;
  const int r16 = lane & 15, kg = lane >> 4;
  const int mi = blk >> 5;          // 0..7
  const int di = blk & 31;          // 0..31
  __shared__ f32x4 pacc[4][5][64];  // 20 KB split-K partials

  const bf16* bp0 = WT_g + (size_t)(0 * 32 + di) * 16384 + lane * 8;
  const bf16* bp1 = WT_g + (size_t)(1 * 32 + di) * 16384 + lane * 8;
  const bf16* bp2 = WT_g + (size_t)(2 * 32 + di) * 16384 + lane * 8;
  const bf16* bp3 = WT_g + (size_t)(3 * 32 + di) * 16384 + lane * 8;
  const bf16* bp4 = WT_g + (size_t)(4 * 32 + di) * 16384 + lane * 8;
  const int d = di * 16 + r16;
  const float bi0 = bgx[d], bi1 = bgx[512 + d], bi2 = bgx[1024 + d];
  const float bi3 = bgx[1536 + d], bi4 = bgx[2048 + d];

  for (int tt = 0; tt < T_; ++tt) {
    const bf16* ap = A1 + (size_t)tt * 131072 + (size_t)mi * 16384 + lane * 8;
    f32x4 acc[5];
#pragma unroll
    for (int g = 0; g < 5; g++) acc[g] = f32x4{0.f, 0.f, 0.f, 0.f};
#pragma unroll 2
    for (int kk = 0; kk < 8; kk++) {
      size_t o = (size_t)(wv * 8 + kk) * 512;
      bf16x8 a  = *(const bf16x8*)(const void*)(ap + o);
      bf16x8 b0 = *(const bf16x8*)(const void*)(bp0 + o);
      bf16x8 b1 = *(const bf16x8*)(const void*)(bp1 + o);
      bf16x8 b2 = *(const bf16x8*)(const void*)(bp2 + o);
      bf16x8 b3 = *(const bf16x8*)(const void*)(bp3 + o);
      bf16x8 b4 = *(const bf16x8*)(const void*)(bp4 + o);
      acc[0] = __builtin_amdgcn_mfma_f32_16x16x32_bf16(a, b0, acc[0], 0, 0, 0);
      acc[1] = __builtin_amdgcn_mfma_f32_16x16x32_bf16(a, b1, acc[1], 0, 0, 0);
      acc[2] = __builtin_amdgcn_mfma_f32_16x16x32_bf16(a, b2, acc[2], 0, 0, 0);
      acc[3] = __builtin_amdgcn_mfma_f32_16x16x32_bf16(a, b3, acc[3], 0, 0, 0);
      acc[4] = __builtin_amdgcn_mfma_f32_16x16x32_bf16(a, b4, acc[4], 0, 0, 0);
    }
#pragma unroll
    for (int g = 0; g < 5; g++) pacc[wv][g][lane] = acc[g];
    __syncthreads();
    if (wv == 0) {
      f32x4 g0 = pacc[0][0][lane] + pacc[1][0][lane] + pacc[2][0][lane] + pacc[3][0][lane];
      f32x4 g1 = pacc[0][1][lane] + pacc[1][1][lane] + pacc[2][1][lane] + pacc[3][1][lane];
      f32x4 g2 = pacc[0][2][lane] + pacc[1][2][lane] + pacc[2][2][lane] + pacc[3][2][lane];
      f32x4 g3 = pacc[0][3][lane] + pacc[1][3][lane] + pacc[2][3][lane] + pacc[3][3][lane];
      f32x4 g4 = pacc[0][4][lane] + pacc[1][4][lane] + pacc[2][4][lane] + pacc[3][4][lane];
      bf16* hnext = A1 + (size_t)(tt + 1) * 131072;
      bf16* pA = projA + (size_t)tt * 131072;
      bf16* AagT = Aag + (size_t)tt * 131072;
#pragma unroll
      for (int r = 0; r < 4; r++) {
        int m = mi * 16 + kg * 4 + r;
        float cn = sigf(g1[r] + bi1) * cbuf[m * 512 + d] +
                   sigf(g0[r] + bi0) * tanh_fast(g2[r] + bi2);
        float tcn = tanh_fast(cn);
        float hn = sigf(g3[r] + bi3) * tcn;
        float ss = sigf(g4[r] + bi4) * tcn;
        cbuf[m * 512 + d] = cn;
        size_t plo = pidx(m, d, 1024), phi = pidx(m, 512 + d, 1024);
        float hn1 = __shfl_down(hn, 1);
        float ss1 = __shfl_down(ss, 1);
        if (!(r16 & 1)) {
          unsigned hp = (unsigned)(unsigned short)f2bs(hn) |
                        ((unsigned)(unsigned short)f2bs(hn1) << 16);
          unsigned sp = (unsigned)(unsigned short)f2bs(ss) |
                        ((unsigned)(unsigned short)f2bs(ss1) << 16);
          *(unsigned*)(void*)(pA + plo) = hp;       // normal (post-scan reader)
          *(unsigned*)(void*)(AagT + plo) = hp;     // normal (post-scan reader)
          *(unsigned*)(void*)(AagT + phi) = sp;
          cst_u32((unsigned*)(void*)(hnext + phi), hp);  // sc1: in-scan reader
        }
      }
    }
    if (tt < T_ - 1) gbar(bar);
  }
}

// ---- batched e-scores + softmax for all (b, t); grid (128, 25) ----
__global__ __launch_bounds__(256) void e_batch(
    const bf16* __restrict__ attv, const float* __restrict__ agsw_all,
    const float* __restrict__ w_a, const int* __restrict__ clen,
    float* __restrict__ alphas, float* __restrict__ betas,
    float* __restrict__ alphas_raw, float* __restrict__ betas_raw)
{
  __shared__ float sh[200];
  __shared__ float red[8];
  int b = blockIdx.x, t = blockIdx.y;
  int tid = threadIdx.x, wv = tid >> 6, lane = tid & 63;
  const float* ag = agsw_all + ((size_t)t * 128 + b) * 1024;
  int a0 = lane * 8;
  float ag8[8], wa8[8], sw8[8];
#pragma unroll
  for (int j = 0; j < 8; j++) {
    ag8[j] = ag[a0 + j];
    wa8[j] = w_a[a0 + j];
    sw8[j] = ag[512 + a0 + j];
  }
  for (int base = wv; base < 197; base += 16) {
    bf16x8 av[4];
#pragma unroll
    for (int q = 0; q < 4; q++) {
      int l = base + 4 * q;
      if (l < 196)
        av[q] = *(const bf16x8*)(const void*)(attv + ((size_t)(b * 196 + l)) * 512 + a0);
    }
#pragma unroll
    for (int q = 0; q < 4; q++) {
      int l = base + 4 * q;
      if (l > 196) continue;    // wave-uniform
      float part = 0.f;
      if (l < 196) {
#pragma unroll
        for (int j = 0; j < 8; j++) part += wa8[j] * tanh_fast(b2f(av[q][j]) + ag8[j]);
      } else {
#pragma unroll
        for (int j = 0; j < 8; j++) part += wa8[j] * tanh_fast(sw8[j] + ag8[j]);
      }
      part = wred_sum(part);
      if (lane == 0) sh[l] = part;
    }
  }
  __syncthreads();
  float v = (tid < 197) ? sh[tid] : -1e30f;
  float mx = wred_max(v);
  if (lane == 0) red[wv] = mx;
  __syncthreads();
  mx = fmaxf(fmaxf(red[0], red[1]), fmaxf(red[2], red[3]));
  float p = (tid < 197) ? __expf(v - mx) : 0.f;
  float sm = wred_sum(p);
  if (lane == 0) red[4 + wv] = sm;
  __syncthreads();
  float inv = 1.f / (red[4] + red[5] + red[6] + red[7]);
  float a = p * inv;
  int dec = clen[b] - 1; if (dec < 1) dec = 1;
  float act = (t < dec) ? 1.f : 0.f;
  if (tid < 196) {
    alphas[(size_t)b * (T_ * L_) + (size_t)t * L_ + tid] = a * act;
    alphas_raw[(size_t)b * (T_ * L_) + (size_t)t * L_ + tid] = a;
  }
  if (tid == 196) {
    betas[b * T_ + t] = a * act;
    betas_raw[b * T_ + t] = a;
  }
}

// ---- tail: ctx(b,t,:) = alpha_raw(b,t,:) @ enc(b) + beta*s ; write projA ctx ----
__global__ __launch_bounds__(256) void ctx_tail(
    const float* __restrict__ alphas_raw, const float* __restrict__ betas_raw,
    const bf16* __restrict__ enc_r, const bf16* __restrict__ Aag,
    bf16* __restrict__ projA)
{
  int b = blockIdx.x, cs = blockIdx.y, tid = threadIdx.x;
  __shared__ float al[T_ * 200];
  for (int i = tid; i < T_ * 196; i += 256) {
    al[(i / 196) * 200 + (i % 196)] = alphas_raw[(size_t)b * (T_ * 196) + i];
  }
  __syncthreads();
  int ch = cs * 256 + tid;
  float acc[T_];
#pragma unroll
  for (int t = 0; t < T_; t++) acc[t] = 0.f;
  const short* ep = (const short*)(const void*)(enc_r) + (size_t)b * 196 * 512 + ch;
#pragma unroll 4
  for (int l = 0; l < 196; l++) {
    float e = b2f(ep[(size_t)l * 512]);
#pragma unroll
    for (int t = 0; t < T_; t++) acc[t] += al[t * 200 + l] * e;
  }
#pragma unroll
  for (int t = 0; t < T_; t++) {
    float beta = betas_raw[b * T_ + t];
    float sv = b2f(((const short*)(const void*)Aag)[(size_t)t * 131072 + pidx(b, 512 + ch, 1024)]);
    projA[(size_t)t * 131072 + pidx(b, 512 + ch, 1024)] = f2b(acc[t] + beta * sv);
  }
}

enum { EPI_F32 = 0, EPI_BF16 = 1, EPI_INIT = 2, EPI_PROJ = 3, EPI_OUT = 4 };

// C = A (MxK packed) @ BT^T (BT: NxK packed), + bias.
template<int MFRAG, int NFRAG, int EPI>
__global__ __launch_bounds__(256) void gemm_pk(
    const bf16* __restrict__ A, const bf16* __restrict__ BT,
    const float* __restrict__ bias, void* __restrict__ Cp,
    const bf16* __restrict__ auxA, float* __restrict__ auxB,
    int M, int N, int K, int ldc, int R0)
{
  const int lane = threadIdx.x & 63;
  const int wv = threadIdx.x >> 6;
  const int r16 = lane & 15;
  const int kg = lane >> 4;
  const int m0 = blockIdx.x * (MFRAG * 16);
  const int n0 = blockIdx.y * (NFRAG * 64) + wv * (NFRAG * 16);
  const int KT = K >> 5;

  f32x4 acc[MFRAG][NFRAG];
#pragma unroll
  for (int i = 0; i < MFRAG; i++)
#pragma unroll
    for (int j = 0; j < NFRAG; j++) acc[i][j] = f32x4{0.f, 0.f, 0.f, 0.f};

  const bf16* ap = A + (size_t)(m0 >> 4) * KT * 512 + lane * 8;
  const bf16* bp = BT + (size_t)(n0 >> 4) * KT * 512 + lane * 8;

#pragma unroll 4
  for (int kt = 0; kt < KT; kt++) {
    bf16x8 af[MFRAG], bfr[NFRAG];
#pragma unroll
    for (int i = 0; i < MFRAG; i++)
      af[i] = *(const bf16x8*)(const void*)(ap + ((size_t)i * KT + kt) * 512);
#pragma unroll
    for (int j = 0; j < NFRAG; j++)
      bfr[j] = *(const bf16x8*)(const void*)(bp + ((size_t)j * KT + kt) * 512);
#pragma unroll
    for (int i = 0; i < MFRAG; i++)
#pragma unroll
      for (int j = 0; j < NFRAG; j++)
        acc[i][j] = __builtin_amdgcn_mfma_f32_16x16x32_bf16(af[i], bfr[j], acc[i][j], 0, 0, 0);
  }

#pragma unroll
  for (int i = 0; i < MFRAG; i++)
#pragma unroll
    for (int j = 0; j < NFRAG; j++)
#pragma unroll
      for (int r = 0; r < 4; r++) {
        int m = m0 + i * 16 + kg * 4 + r;
        int n = n0 + j * 16 + r16;
        if (n >= N) continue;
        float v = acc[i][j][r] + bias[n];
        if constexpr (EPI == EPI_F32) {
          ((float*)Cp)[(size_t)m * ldc + n] = v;
        } else if constexpr (EPI == EPI_BF16) {
          ((bf16*)Cp)[(size_t)m * ldc + n] = f2b(v);
        } else if constexpr (EPI == EPI_INIT) {
          float tv = tanhf(v);
          if (n < 512) ((bf16*)Cp)[pidx(m, 512 + n, 1024)] = f2b(tv);  // h0 -> A1[0]
          else auxB[(size_t)m * 512 + (n - 512)] = tv;                 // c0 (f32)
        } else if constexpr (EPI == EPI_PROJ) {
          int t = m >> 7, b = m & 127;
          v += b2f(((const short*)auxA)[(size_t)t * 131072 + pidx(b, n, 1024)]);  // + x
          ((bf16*)Cp)[pidx(m, n, 512)] = f2b(v);
        } else {  // EPI_OUT: preds[b, t, n], row = t*128+b
          int t = m >> 7, b = m & 127;
          ((float*)Cp)[(size_t)b * (T_ * V_) + (size_t)t * V_ + n] = v;
        }
      }
}

// Packed-transpose: dst (nrows x K packed) = [top; bot]^T with zero padding.
__global__ void trans_pack(const float* __restrict__ top, const float* __restrict__ bot,
                           bf16* __restrict__ dst, int ncols, long nElem8, int ktop, int K)
{
  int KT = K >> 5;
  for (long t8 = (long)blockIdx.x * blockDim.x + threadIdx.x; t8 < nElem8;
       t8 += (long)gridDim.x * blockDim.x) {
    int r = (int)(t8 & 15);
    int kg = (int)((t8 >> 4) & 3);
    long tile = t8 >> 6;
    int kt = (int)(tile % KT);
    int rt = (int)(tile / KT);
    int n = rt * 16 + r;
    int kb = kt * 32 + kg * 8;
    bf16x8 out;
#pragma unroll
    for (int j = 0; j < 8; j++) {
      int k = kb + j;
      float v = 0.f;
      if (n < ncols) {
        if (k < ktop) { if (top) v = top[(size_t)k * ncols + n]; }
        else if (bot) { v = bot[(size_t)(k - ktop) * ncols + n]; }
      }
      out[j] = f2bs(v);
    }
    *(bf16x8*)(void*)(dst + t8 * 8) = out;
  }
}

// enc (f32 row-major) -> enc_p (bf16 packed) AND enc_r (bf16 row-major)
__global__ void conv_pack(const float* __restrict__ src, bf16* __restrict__ dst,
                          bf16* __restrict__ dst_row, long nElem8)
{
  for (long t8 = (long)blockIdx.x * blockDim.x + threadIdx.x; t8 < nElem8;
       t8 += (long)gridDim.x * blockDim.x) {
    int r = (int)(t8 & 15);
    int kg = (int)((t8 >> 4) & 3);
    long tile = t8 >> 6;
    int kt = (int)(tile & 15);           // KT = 16 (K=512)
    int rt = (int)(tile >> 4);
    size_t rowoff = ((size_t)(rt * 16 + r)) * 512 + kt * 32 + kg * 8;
    const float* s = src + rowoff;
    bf16x8 out;
#pragma unroll
    for (int j = 0; j < 8; j++) out[j] = f2bs(s[j]);
    *(bf16x8*)(void*)(dst + t8 * 8) = out;
    *(bf16x8*)(void*)(dst_row + rowoff) = out;
  }
}

__global__ void bias_comb(const float* __restrict__ b_lstm, const float* __restrict__ b_s,
                          const float* __restrict__ b_g, const float* __restrict__ b_sa,
                          const float* __restrict__ b_Lh, const float* __restrict__ b_Lz,
                          const float* __restrict__ b_ih, const float* __restrict__ b_ic,
                          float* __restrict__ bg, float* __restrict__ ba,
                          float* __restrict__ bp, float* __restrict__ bi)
{
  int i = blockIdx.x * blockDim.x + threadIdx.x;
  if (i < 2560) bg[i] = (i < 2048) ? b_lstm[i] : b_s[i - 2048];
  if (i < 1024) ba[i] = (i < 512) ? b_g[i] : b_sa[i - 512];
  if (i < 512)  bp[i] = b_Lh[i] + b_Lz[i];
  if (i < 1024) bi[i] = (i < 512) ? b_ih[i] : b_ic[i - 512];
}

__global__ __launch_bounds__(128) void mean_enc(const float* __restrict__ enc,
                                                bf16* __restrict__ mb)
{
  int b = blockIdx.x, c = blockIdx.y * 128 + threadIdx.x;
  float s = 0.f;
  for (int l = 0; l < L_; l++) s += enc[((size_t)b * L_ + l) * 512 + c];
  mb[pidx(b, c, 512)] = f2b(s * (1.f / (float)L_));
}

__global__ void gather_x(const float* __restrict__ emb, const int* __restrict__ caps,
                         bf16* __restrict__ A1)
{
  int tb = blockIdx.x;          // t*128 + b
  int t = tb >> 7, b = tb & 127;
  int word = caps[b * 26 + t];
  int c0 = threadIdx.x * 8;
  const float* src = emb + (size_t)word * 512 + c0;
  bf16* dst = A1 + (size_t)t * (128 * 1024) + pidx(b, c0, 1024);
  bf16x8 out;
#pragma unroll
  for (int j = 0; j < 8; j++) out[j] = f2bs(src[j]);
  *(bf16x8*)(void*)dst = out;
}

extern "C" void kernel_launch(void* const* d_in, const int* in_sizes, int n_in,
                              void* d_out, int out_size, void* d_ws, size_t ws_size,
                              hipStream_t stream)
{
  const float* enc      = (const float*)d_in[0];
  const int*   caps     = (const int*)d_in[1];
  const int*   clen     = (const int*)d_in[2];
  const float* emb      = (const float*)d_in[3];
  const float* W_ih     = (const float*)d_in[4];
  const float* W_hh     = (const float*)d_in[5];
  const float* b_lstm   = (const float*)d_in[6];
  const float* Wx_s     = (const float*)d_in[7];
  const float* Wh_s     = (const float*)d_in[8];
  const float* b_s      = (const float*)d_in[9];
  const float* W_v      = (const float*)d_in[10];
  const float* b_v      = (const float*)d_in[11];
  const float* W_g      = (const float*)d_in[12];
  const float* b_g      = (const float*)d_in[13];
  const float* W_s_att  = (const float*)d_in[14];
  const float* b_sa     = (const float*)d_in[15];
  const float* w_a      = (const float*)d_in[16];
  const float* W_init_h = (const float*)d_in[17];
  const float* b_init_h = (const float*)d_in[18];
  const float* W_init_c = (const float*)d_in[19];
  const float* b_init_c = (const float*)d_in[20];
  const float* W_Lh     = (const float*)d_in[21];
  const float* b_Lh     = (const float*)d_in[22];
  const float* W_Lz     = (const float*)d_in[23];
  const float* b_Lz     = (const float*)d_in[24];
  const float* W_Lo     = (const float*)d_in[25];
  const float* b_Lo     = (const float*)d_in[26];

  float* preds  = (float*)d_out;
  float* alphas = preds + (size_t)B_ * T_ * V_;
  float* betas  = alphas + (size_t)B_ * T_ * L_;

  char* ws = (char*)d_ws;
  size_t off = 0;
  auto alloc = [&](size_t bytes) -> void* {
    void* p = ws + off;
    off = (off + bytes + 255) & ~(size_t)255;
    return p;
  };
  bf16*  enc_p  = (bf16*)alloc((size_t)B_ * L_ * 512 * 2);   // dead after att_v GEMM
  bf16*  enc_r  = (bf16*)alloc((size_t)B_ * L_ * 512 * 2);
  bf16*  attv_b = (bf16*)alloc((size_t)B_ * L_ * 512 * 2);
  bf16*  WT_g   = (bf16*)alloc((size_t)2560 * 1024 * 2);
  bf16*  WT_a   = (bf16*)alloc((size_t)1024 * 1024 * 2);
  bf16*  WT_p   = (bf16*)alloc((size_t)512 * 1024 * 2);
  bf16*  WT_lo  = (bf16*)alloc((size_t)10240 * 512 * 2);
  bf16*  WT_v   = (bf16*)alloc((size_t)512 * 512 * 2);
  bf16*  WT_i   = (bf16*)alloc((size_t)1024 * 512 * 2);
  float* bgx    = (float*)alloc(2560 * 4);
  float* bax    = (float*)alloc(1024 * 4);
  float* bpx    = (float*)alloc(512 * 4);
  float* bix    = (float*)alloc(1024 * 4);
  bf16*  mean_b = (bf16*)alloc(128 * 512 * 2);
  bf16*  A1     = (bf16*)alloc((size_t)(T_ + 1) * 128 * 1024 * 2);
  bf16*  projA  = (bf16*)alloc((size_t)T_ * 128 * 1024 * 2);
  bf16*  projb  = (bf16*)alloc((size_t)T_ * 128 * 512 * 2);
  float* cbuf   = (float*)alloc(128 * 512 * 4);
  unsigned* bar = (unsigned*)alloc(4096);
  if (off > ws_size) return;  // loud validation failure if ws too small

  // Overlay post-scan buffers onto dead enc_p (25,690,112 B):
  //   agsw_all 13,107,200 | Aag 6,553,600 | alphas_raw 2,508,800 | betas_raw 12,800
  float* agsw_all   = (float*)enc_p;
  bf16*  Aag        = (bf16*)((char*)enc_p + 13107200);
  float* alphas_raw = (float*)((char*)enc_p + 19660800);
  float* betas_raw  = (float*)((char*)enc_p + 22169600);

  hipMemsetAsync(bar, 0, 4096, stream);

  // ---- prep ----
  bias_comb<<<dim3(10), dim3(256), 0, stream>>>(b_lstm, b_s, b_g, b_sa, b_Lh, b_Lz,
                                                b_init_h, b_init_c, bgx, bax, bpx, bix);
  auto TP = [&](const float* top, const float* bot, bf16* dst, int ncols, int nrows,
                int ktop, int K) {
    long n8 = (long)nrows * K / 8;
    int blocks = (int)((n8 + 255) / 256);
    if (blocks > 4096) blocks = 4096;
    trans_pack<<<dim3(blocks), dim3(256), 0, stream>>>(top, bot, dst, ncols, n8, ktop, K);
  };
  TP(W_ih, W_hh, WT_g, 2048, 2048, 512, 1024);
  TP(Wx_s, Wh_s, WT_g + (size_t)2048 * 1024, 512, 512, 512, 1024);
  TP(W_Lh, W_Lz, WT_p, 512, 512, 512, 1024);
  TP(W_g, nullptr, WT_a, 512, 512, 512, 1024);
  TP(nullptr, W_s_att, WT_a + (size_t)512 * 1024, 512, 512, 512, 1024);
  TP(W_Lo, nullptr, WT_lo, 10000, 10240, 512, 512);
  TP(W_v, nullptr, WT_v, 512, 512, 512, 512);
  TP(W_init_h, nullptr, WT_i, 512, 512, 512, 512);
  TP(W_init_c, nullptr, WT_i + (size_t)512 * 512, 512, 512, 512, 512);
  conv_pack<<<dim3(4096), dim3(256), 0, stream>>>(enc, enc_p, enc_r,
                                                  (long)B_ * L_ * 512 / 8);
  mean_enc<<<dim3(128, 4), dim3(128), 0, stream>>>(enc, mean_b);
  gather_x<<<dim3(T_ * 128), dim3(64), 0, stream>>>(emb, caps, A1);

  // h0 -> A1[0] h-slot (packed bf16), c0 -> cbuf (f32)
  gemm_pk<1, 1, EPI_INIT><<<dim3(8, 16), dim3(256), 0, stream>>>(
      mean_b, WT_i, bix, (void*)A1, nullptr, cbuf, 128, 1024, 512, 0, 0);
  // att_v = enc @ W_v + b_v   (bf16 row-major out) — last consumer of enc_p
  gemm_pk<4, 2, EPI_BF16><<<dim3(392, 4), dim3(256), 0, stream>>>(
      enc_p, WT_v, b_v, attv_b, nullptr, nullptr, B_ * L_, 512, 512, 512, 0);

  // ---- persistent 25-step LSTM-only scan (1 barrier/step) ----
  scan26<<<dim3(NBLK), dim3(256), 0, stream>>>(A1, WT_g, bgx, cbuf, Aag, projA, bar);

  // ---- batched attention pipeline ----
  // agsw_all = [h|s]_all @ blockdiag(W_g, W_s_att) + [b_g|b_sa] (3200x1024x1024)
  gemm_pk<4, 2, EPI_F32><<<dim3(50, 8), dim3(256), 0, stream>>>(
      Aag, WT_a, bax, agsw_all, nullptr, nullptr, T_ * 128, 1024, 1024, 1024, 0);
  // e-scores + softmax for all (b,t)
  e_batch<<<dim3(128, 25), dim3(256), 0, stream>>>(
      attv_b, agsw_all, w_a, clen, alphas, betas, alphas_raw, betas_raw);
  // ctx -> projA ctx-slots (reads enc ONCE, batched over all t)
  ctx_tail<<<dim3(128, 2), dim3(256), 0, stream>>>(alphas_raw, betas_raw, enc_r,
                                                   Aag, projA);
  // proj = x + [h|ctx] @ [W_Lh;W_Lz] + b   (3200 x 512 x 1024, packed out)
  gemm_pk<4, 2, EPI_PROJ><<<dim3(50, 4), dim3(256), 0, stream>>>(
      projA, WT_p, bpx, projb, (const bf16*)A1, nullptr, T_ * 128, 512, 1024, 0, 0);
  // preds = proj @ W_Lo + b_Lo  (3200 x 10000 x 512)
  gemm_pk<4, 4, EPI_OUT><<<dim3(50, 40), dim3(256), 0, stream>>>(
      projb, WT_lo, b_Lo, preds, nullptr, nullptr, T_ * 128, V_, 512, 0, 0);
}

// Round 8
// 525.189 us; speedup vs baseline: 4.3824x; 1.1976x over previous
//
#include <hip/hip_runtime.h>
#include <hip/hip_bf16.h>
#include <cstdint>
#include <cstddef>

using bf16 = __hip_bfloat16;
typedef __attribute__((ext_vector_type(4))) float f32x4;
typedef __attribute__((ext_vector_type(8))) short bf16x8;

#define B_ 128
#define L_ 196
#define T_ 25
#define V_ 10000
#define NBLK 256
#define ESCL 2.885390081777927f   // 2*log2(e): tanh(z) = 1 - 2/(1+exp2(z*ESCL))

__device__ __forceinline__ float b2f(short s) {
  unsigned u = ((unsigned)(unsigned short)s) << 16;
  return __uint_as_float(u);
}
__device__ __forceinline__ bf16 f2b(float f) { return __float2bfloat16(f); }
__device__ __forceinline__ short f2bs(float f) {
  return __builtin_bit_cast(short, __float2bfloat16(f));
}
__device__ __forceinline__ float sigf(float x) { return 1.f / (1.f + __expf(-x)); }
__device__ __forceinline__ float tanh_fast(float x) { return 1.f - 2.f / (1.f + __expf(2.f * x)); }

// sc1 write-through stores (push to L3, cross-XCD visible after vmcnt drain).
// Readers use NORMAL cached loads on addresses never touched earlier in the
// dispatch (cold miss -> L3 -> pushed data). Validated R6.
__device__ __forceinline__ void cst_u32(unsigned* p, unsigned v) {
  __hip_atomic_store(p, v, __ATOMIC_RELAXED, __HIP_MEMORY_SCOPE_AGENT);
}
__device__ __forceinline__ unsigned cld_u32(const unsigned* p) {
  return __hip_atomic_load((unsigned*)p, __ATOMIC_RELAXED, __HIP_MEMORY_SCOPE_AGENT);
}

// Fragment-packed layout: 16x32 tiles, tile-row-major; element (r,c) at
// (((r>>4)*KT + (c>>5))*64 + ((c&31)>>3)*16 + (r&15))*8 + (c&7).
__device__ __forceinline__ size_t pidx(int row, int col, int K) {
  int KT = K >> 5;
  return (((size_t)(row >> 4) * KT + (col >> 5)) * 64 +
          (size_t)(((col & 31) >> 3) * 16 + (row & 15))) * 8 + (col & 7);
}

__device__ __forceinline__ float wred_sum(float x) {
#pragma unroll
  for (int off = 32; off >= 1; off >>= 1) x += __shfl_xor(x, off, 64);
  return x;
}
__device__ __forceinline__ float wred_max(float x) {
#pragma unroll
  for (int off = 32; off >= 1; off >>= 1) x = fmaxf(x, __shfl_xor(x, off, 64));
  return x;
}

// ---- two-level grid barrier: relaxed atomics only ----
__device__ __forceinline__ void gbar(unsigned* bs) {
  __syncthreads();
  if (threadIdx.x == 0) {
    asm volatile("s_waitcnt vmcnt(0)" ::: "memory");
    unsigned* lcnt = bs;         // 16 shards, 128B apart
    unsigned* cnt  = bs + 512;
    unsigned* gen  = bs + 544;
    unsigned g = cld_u32(gen);
    int grp = (int)(blockIdx.x & 15u);
    unsigned a = __hip_atomic_fetch_add(&lcnt[grp * 32], 1u, __ATOMIC_RELAXED,
                                        __HIP_MEMORY_SCOPE_AGENT);
    bool rel = false;
    if ((a & 15u) == 15u) {
      unsigned b = __hip_atomic_fetch_add(cnt, 1u, __ATOMIC_RELAXED,
                                          __HIP_MEMORY_SCOPE_AGENT);
      if ((b & 15u) == 15u) {
        cst_u32(gen, g + 1u);
        rel = true;
      }
    }
    if (!rel) {
      while (cld_u32(gen) == g) __builtin_amdgcn_s_sleep(1);
    }
  }
  __syncthreads();
}

// ---- persistent scan: ONLY the LSTM recurrence; 1 barrier per step ----
// 256 blocks = 8 mi (16-row tiles) x 32 di (16-d tiles). Waves split K 4-way.
__global__ __launch_bounds__(256) void scan26(
    bf16* __restrict__ A1,          // (T_+1) x (128x1024 packed): [x | h]
    const bf16* __restrict__ WT_g,  // 2560x1024 packed
    const float* __restrict__ bgx,  // 2560 combined bias
    float* __restrict__ cbuf,       // 128x512 f32 (block-private tiles)
    bf16* __restrict__ Aag,         // T_ x 128x1024 packed [h|s]  (post-scan)
    bf16* __restrict__ projA,       // T_ x 128x1024 packed [h|ctx] (post-scan)
    unsigned* __restrict__ bar)
{
  const int blk = blockIdx.x;
  const int tid = threadIdx.x;
  const int wv = tid >> 6, lane = tid & 63;
  const int r16 = lane & 15, kg = lane >> 4;
  const int mi = blk >> 5;          // 0..7
  const int di = blk & 31;          // 0..31
  __shared__ f32x4 pacc[4][5][64];  // 20 KB split-K partials

  const bf16* bp0 = WT_g + (size_t)(0 * 32 + di) * 16384 + lane * 8;
  const bf16* bp1 = WT_g + (size_t)(1 * 32 + di) * 16384 + lane * 8;
  const bf16* bp2 = WT_g + (size_t)(2 * 32 + di) * 16384 + lane * 8;
  const bf16* bp3 = WT_g + (size_t)(3 * 32 + di) * 16384 + lane * 8;
  const bf16* bp4 = WT_g + (size_t)(4 * 32 + di) * 16384 + lane * 8;
  const int d = di * 16 + r16;
  const float bi0 = bgx[d], bi1 = bgx[512 + d], bi2 = bgx[1024 + d];
  const float bi3 = bgx[1536 + d], bi4 = bgx[2048 + d];

  for (int tt = 0; tt < T_; ++tt) {
    const bf16* ap = A1 + (size_t)tt * 131072 + (size_t)mi * 16384 + lane * 8;
    f32x4 acc[5];
#pragma unroll
    for (int g = 0; g < 5; g++) acc[g] = f32x4{0.f, 0.f, 0.f, 0.f};
#pragma unroll 2
    for (int kk = 0; kk < 8; kk++) {
      size_t o = (size_t)(wv * 8 + kk) * 512;
      bf16x8 a  = *(const bf16x8*)(const void*)(ap + o);
      bf16x8 b0 = *(const bf16x8*)(const void*)(bp0 + o);
      bf16x8 b1 = *(const bf16x8*)(const void*)(bp1 + o);
      bf16x8 b2 = *(const bf16x8*)(const void*)(bp2 + o);
      bf16x8 b3 = *(const bf16x8*)(const void*)(bp3 + o);
      bf16x8 b4 = *(const bf16x8*)(const void*)(bp4 + o);
      acc[0] = __builtin_amdgcn_mfma_f32_16x16x32_bf16(a, b0, acc[0], 0, 0, 0);
      acc[1] = __builtin_amdgcn_mfma_f32_16x16x32_bf16(a, b1, acc[1], 0, 0, 0);
      acc[2] = __builtin_amdgcn_mfma_f32_16x16x32_bf16(a, b2, acc[2], 0, 0, 0);
      acc[3] = __builtin_amdgcn_mfma_f32_16x16x32_bf16(a, b3, acc[3], 0, 0, 0);
      acc[4] = __builtin_amdgcn_mfma_f32_16x16x32_bf16(a, b4, acc[4], 0, 0, 0);
    }
#pragma unroll
    for (int g = 0; g < 5; g++) pacc[wv][g][lane] = acc[g];
    __syncthreads();
    if (wv == 0) {
      f32x4 g0 = pacc[0][0][lane] + pacc[1][0][lane] + pacc[2][0][lane] + pacc[3][0][lane];
      f32x4 g1 = pacc[0][1][lane] + pacc[1][1][lane] + pacc[2][1][lane] + pacc[3][1][lane];
      f32x4 g2 = pacc[0][2][lane] + pacc[1][2][lane] + pacc[2][2][lane] + pacc[3][2][lane];
      f32x4 g3 = pacc[0][3][lane] + pacc[1][3][lane] + pacc[2][3][lane] + pacc[3][3][lane];
      f32x4 g4 = pacc[0][4][lane] + pacc[1][4][lane] + pacc[2][4][lane] + pacc[3][4][lane];
      bf16* hnext = A1 + (size_t)(tt + 1) * 131072;
      bf16* pA = projA + (size_t)tt * 131072;
      bf16* AagT = Aag + (size_t)tt * 131072;
#pragma unroll
      for (int r = 0; r < 4; r++) {
        int m = mi * 16 + kg * 4 + r;
        float cn = sigf(g1[r] + bi1) * cbuf[m * 512 + d] +
                   sigf(g0[r] + bi0) * tanh_fast(g2[r] + bi2);
        float tcn = tanh_fast(cn);
        float hn = sigf(g3[r] + bi3) * tcn;
        float ss = sigf(g4[r] + bi4) * tcn;
        cbuf[m * 512 + d] = cn;
        size_t plo = pidx(m, d, 1024), phi = pidx(m, 512 + d, 1024);
        float hn1 = __shfl_down(hn, 1);
        float ss1 = __shfl_down(ss, 1);
        if (!(r16 & 1)) {
          unsigned hp = (unsigned)(unsigned short)f2bs(hn) |
                        ((unsigned)(unsigned short)f2bs(hn1) << 16);
          unsigned sp = (unsigned)(unsigned short)f2bs(ss) |
                        ((unsigned)(unsigned short)f2bs(ss1) << 16);
          *(unsigned*)(void*)(pA + plo) = hp;       // normal (post-scan reader)
          *(unsigned*)(void*)(AagT + plo) = hp;     // normal (post-scan reader)
          *(unsigned*)(void*)(AagT + phi) = sp;
          cst_u32((unsigned*)(void*)(hnext + phi), hp);  // sc1: in-scan reader
        }
      }
    }
    if (tt < T_ - 1) gbar(bar);
  }
}

// ---- batched e-scores + softmax for all (b, t); grid (128, 25) ----
// attv and agsw are PRE-SCALED by ESCL, so
//   e = Wsum - 2 * sum_d wa[d] * rcp(1 + exp2(attv'[d] + ag'[d]))
__global__ __launch_bounds__(256) void e_batch(
    const bf16* __restrict__ attv, const float* __restrict__ agsw_all,
    const float* __restrict__ w_a, const int* __restrict__ clen,
    float* __restrict__ alphas, float* __restrict__ betas,
    float* __restrict__ alphas_raw, float* __restrict__ betas_raw)
{
  __shared__ float sh[200];
  __shared__ float red[8];
  int b = blockIdx.x, t = blockIdx.y;
  int tid = threadIdx.x, wv = tid >> 6, lane = tid & 63;
  const float* ag = agsw_all + ((size_t)t * 128 + b) * 1024;
  int a0 = lane * 8;
  float ag8[8], wa8[8], sw8[8];
  float wsum = 0.f;
#pragma unroll
  for (int j = 0; j < 8; j++) {
    ag8[j] = ag[a0 + j];
    wa8[j] = w_a[a0 + j];
    sw8[j] = ag[512 + a0 + j];
    wsum += wa8[j];
  }
  wsum = wred_sum(wsum);
  for (int base = wv; base < 197; base += 16) {
    bf16x8 av[4];
#pragma unroll
    for (int q = 0; q < 4; q++) {
      int l = base + 4 * q;
      if (l < 196)
        av[q] = *(const bf16x8*)(const void*)(attv + ((size_t)(b * 196 + l)) * 512 + a0);
    }
#pragma unroll
    for (int q = 0; q < 4; q++) {
      int l = base + 4 * q;
      if (l > 196) continue;    // wave-uniform
      float part = 0.f;
      if (l < 196) {
#pragma unroll
        for (int j = 0; j < 8; j++) {
          float z = b2f(av[q][j]) + ag8[j];
          float E = __builtin_amdgcn_exp2f(z);
          part = fmaf(wa8[j], __builtin_amdgcn_rcpf(1.f + E), part);
        }
      } else {
#pragma unroll
        for (int j = 0; j < 8; j++) {
          float z = sw8[j] + ag8[j];
          float E = __builtin_amdgcn_exp2f(z);
          part = fmaf(wa8[j], __builtin_amdgcn_rcpf(1.f + E), part);
        }
      }
      part = wred_sum(part);
      if (lane == 0) sh[l] = wsum - 2.f * part;
    }
  }
  __syncthreads();
  float v = (tid < 197) ? sh[tid] : -1e30f;
  float mx = wred_max(v);
  if (lane == 0) red[wv] = mx;
  __syncthreads();
  mx = fmaxf(fmaxf(red[0], red[1]), fmaxf(red[2], red[3]));
  float p = (tid < 197) ? __expf(v - mx) : 0.f;
  float sm = wred_sum(p);
  if (lane == 0) red[4 + wv] = sm;
  __syncthreads();
  float inv = 1.f / (red[4] + red[5] + red[6] + red[7]);
  float a = p * inv;
  int dec = clen[b] - 1; if (dec < 1) dec = 1;
  float act = (t < dec) ? 1.f : 0.f;
  if (tid < 196) {
    alphas[(size_t)b * (T_ * L_) + (size_t)t * L_ + tid] = a * act;
    alphas_raw[(size_t)b * (T_ * L_) + (size_t)t * L_ + tid] = a;
  }
  if (tid == 196) {
    betas[b * T_ + t] = a * act;
    betas_raw[b * T_ + t] = a;
  }
}

// ---- tail: ctx(b,t,:) = alpha_raw(b,t,:) @ enc(b) + beta*s ; write projA ctx ----
__global__ __launch_bounds__(256) void ctx_tail(
    const float* __restrict__ alphas_raw, const float* __restrict__ betas_raw,
    const bf16* __restrict__ enc_r, const bf16* __restrict__ Aag,
    bf16* __restrict__ projA)
{
  int b = blockIdx.x, cs = blockIdx.y, tid = threadIdx.x;
  __shared__ float al[T_ * 200];
  for (int i = tid; i < T_ * 196; i += 256) {
    al[(i / 196) * 200 + (i % 196)] = alphas_raw[(size_t)b * (T_ * 196) + i];
  }
  __syncthreads();
  int ch = cs * 256 + tid;
  float acc[T_];
#pragma unroll
  for (int t = 0; t < T_; t++) acc[t] = 0.f;
  const short* ep = (const short*)(const void*)(enc_r) + (size_t)b * 196 * 512 + ch;
#pragma unroll 4
  for (int l = 0; l < 196; l++) {
    float e = b2f(ep[(size_t)l * 512]);
#pragma unroll
    for (int t = 0; t < T_; t++) acc[t] += al[t * 200 + l] * e;
  }
#pragma unroll
  for (int t = 0; t < T_; t++) {
    float beta = betas_raw[b * T_ + t];
    float sv = b2f(((const short*)(const void*)Aag)[(size_t)t * 131072 + pidx(b, 512 + ch, 1024)]);
    projA[(size_t)t * 131072 + pidx(b, 512 + ch, 1024)] = f2b(acc[t] + beta * sv);
  }
}

enum { EPI_F32 = 0, EPI_BF16 = 1, EPI_INIT = 2, EPI_PROJ = 3, EPI_OUT = 4 };

// C = A (MxK packed) @ BT^T (BT: NxK packed), + bias, optionally * oscale.
template<int MFRAG, int NFRAG, int EPI>
__global__ __launch_bounds__(256) void gemm_pk(
    const bf16* __restrict__ A, const bf16* __restrict__ BT,
    const float* __restrict__ bias, void* __restrict__ Cp,
    const bf16* __restrict__ auxA, float* __restrict__ auxB,
    int M, int N, int K, int ldc, float oscale)
{
  const int lane = threadIdx.x & 63;
  const int wv = threadIdx.x >> 6;
  const int r16 = lane & 15;
  const int kg = lane >> 4;
  const int m0 = blockIdx.x * (MFRAG * 16);
  const int n0 = blockIdx.y * (NFRAG * 64) + wv * (NFRAG * 16);
  const int KT = K >> 5;

  f32x4 acc[MFRAG][NFRAG];
#pragma unroll
  for (int i = 0; i < MFRAG; i++)
#pragma unroll
    for (int j = 0; j < NFRAG; j++) acc[i][j] = f32x4{0.f, 0.f, 0.f, 0.f};

  const bf16* ap = A + (size_t)(m0 >> 4) * KT * 512 + lane * 8;
  const bf16* bp = BT + (size_t)(n0 >> 4) * KT * 512 + lane * 8;

#pragma unroll 4
  for (int kt = 0; kt < KT; kt++) {
    bf16x8 af[MFRAG], bfr[NFRAG];
#pragma unroll
    for (int i = 0; i < MFRAG; i++)
      af[i] = *(const bf16x8*)(const void*)(ap + ((size_t)i * KT + kt) * 512);
#pragma unroll
    for (int j = 0; j < NFRAG; j++)
      bfr[j] = *(const bf16x8*)(const void*)(bp + ((size_t)j * KT + kt) * 512);
#pragma unroll
    for (int i = 0; i < MFRAG; i++)
#pragma unroll
      for (int j = 0; j < NFRAG; j++)
        acc[i][j] = __builtin_amdgcn_mfma_f32_16x16x32_bf16(af[i], bfr[j], acc[i][j], 0, 0, 0);
  }

#pragma unroll
  for (int i = 0; i < MFRAG; i++)
#pragma unroll
    for (int j = 0; j < NFRAG; j++)
#pragma unroll
      for (int r = 0; r < 4; r++) {
        int m = m0 + i * 16 + kg * 4 + r;
        int n = n0 + j * 16 + r16;
        if (n >= N) continue;
        float v = acc[i][j][r] + bias[n];
        if constexpr (EPI == EPI_F32) {
          ((float*)Cp)[(size_t)m * ldc + n] = v * oscale;
        } else if constexpr (EPI == EPI_BF16) {
          ((bf16*)Cp)[(size_t)m * ldc + n] = f2b(v * oscale);
        } else if constexpr (EPI == EPI_INIT) {
          float tv = tanhf(v);
          if (n < 512) ((bf16*)Cp)[pidx(m, 512 + n, 1024)] = f2b(tv);  // h0 -> A1[0]
          else auxB[(size_t)m * 512 + (n - 512)] = tv;                 // c0 (f32)
        } else if constexpr (EPI == EPI_PROJ) {
          int t = m >> 7, b = m & 127;
          v += b2f(((const short*)auxA)[(size_t)t * 131072 + pidx(b, n, 1024)]);  // + x
          ((bf16*)Cp)[pidx(m, n, 512)] = f2b(v);
        } else {  // EPI_OUT: preds[b, t, n], row = t*128+b
          int t = m >> 7, b = m & 127;
          ((float*)Cp)[(size_t)b * (T_ * V_) + (size_t)t * V_ + n] = v;
        }
      }
}

// Packed-transpose: dst (nrows x K packed) = [top; bot]^T with zero padding.
__global__ void trans_pack(const float* __restrict__ top, const float* __restrict__ bot,
                           bf16* __restrict__ dst, int ncols, long nElem8, int ktop, int K)
{
  int KT = K >> 5;
  for (long t8 = (long)blockIdx.x * blockDim.x + threadIdx.x; t8 < nElem8;
       t8 += (long)gridDim.x * blockDim.x) {
    int r = (int)(t8 & 15);
    int kg = (int)((t8 >> 4) & 3);
    long tile = t8 >> 6;
    int kt = (int)(tile % KT);
    int rt = (int)(tile / KT);
    int n = rt * 16 + r;
    int kb = kt * 32 + kg * 8;
    bf16x8 out;
#pragma unroll
    for (int j = 0; j < 8; j++) {
      int k = kb + j;
      float v = 0.f;
      if (n < ncols) {
        if (k < ktop) { if (top) v = top[(size_t)k * ncols + n]; }
        else if (bot) { v = bot[(size_t)(k - ktop) * ncols + n]; }
      }
      out[j] = f2bs(v);
    }
    *(bf16x8*)(void*)(dst + t8 * 8) = out;
  }
}

// enc (f32 row-major) -> enc_p (bf16 packed) AND enc_r (bf16 row-major)
__global__ void conv_pack(const float* __restrict__ src, bf16* __restrict__ dst,
                          bf16* __restrict__ dst_row, long nElem8)
{
  for (long t8 = (long)blockIdx.x * blockDim.x + threadIdx.x; t8 < nElem8;
       t8 += (long)gridDim.x * blockDim.x) {
    int r = (int)(t8 & 15);
    int kg = (int)((t8 >> 4) & 3);
    long tile = t8 >> 6;
    int kt = (int)(tile & 15);           // KT = 16 (K=512)
    int rt = (int)(tile >> 4);
    size_t rowoff = ((size_t)(rt * 16 + r)) * 512 + kt * 32 + kg * 8;
    const float* s = src + rowoff;
    bf16x8 out;
#pragma unroll
    for (int j = 0; j < 8; j++) out[j] = f2bs(s[j]);
    *(bf16x8*)(void*)(dst + t8 * 8) = out;
    *(bf16x8*)(void*)(dst_row + rowoff) = out;
  }
}

__global__ void bias_comb(const float* __restrict__ b_lstm, const float* __restrict__ b_s,
                          const float* __restrict__ b_g, const float* __restrict__ b_sa,
                          const float* __restrict__ b_Lh, const float* __restrict__ b_Lz,
                          const float* __restrict__ b_ih, const float* __restrict__ b_ic,
                          float* __restrict__ bg, float* __restrict__ ba,
                          float* __restrict__ bp, float* __restrict__ bi)
{
  int i = blockIdx.x * blockDim.x + threadIdx.x;
  if (i < 2560) bg[i] = (i < 2048) ? b_lstm[i] : b_s[i - 2048];
  if (i < 1024) ba[i] = (i < 512) ? b_g[i] : b_sa[i - 512];
  if (i < 512)  bp[i] = b_Lh[i] + b_Lz[i];
  if (i < 1024) bi[i] = (i < 512) ? b_ih[i] : b_ic[i - 512];
}

__global__ __launch_bounds__(128) void mean_enc(const float* __restrict__ enc,
                                                bf16* __restrict__ mb)
{
  int b = blockIdx.x, c = blockIdx.y * 128 + threadIdx.x;
  float s = 0.f;
  for (int l = 0; l < L_; l++) s += enc[((size_t)b * L_ + l) * 512 + c];
  mb[pidx(b, c, 512)] = f2b(s * (1.f / (float)L_));
}

__global__ void gather_x(const float* __restrict__ emb, const int* __restrict__ caps,
                         bf16* __restrict__ A1)
{
  int tb = blockIdx.x;          // t*128 + b
  int t = tb >> 7, b = tb & 127;
  int word = caps[b * 26 + t];
  int c0 = threadIdx.x * 8;
  const float* src = emb + (size_t)word * 512 + c0;
  bf16* dst = A1 + (size_t)t * (128 * 1024) + pidx(b, c0, 1024);
  bf16x8 out;
#pragma unroll
  for (int j = 0; j < 8; j++) out[j] = f2bs(src[j]);
  *(bf16x8*)(void*)dst = out;
}

extern "C" void kernel_launch(void* const* d_in, const int* in_sizes, int n_in,
                              void* d_out, int out_size, void* d_ws, size_t ws_size,
                              hipStream_t stream)
{
  const float* enc      = (const float*)d_in[0];
  const int*   caps     = (const int*)d_in[1];
  const int*   clen     = (const int*)d_in[2];
  const float* emb      = (const float*)d_in[3];
  const float* W_ih     = (const float*)d_in[4];
  const float* W_hh     = (const float*)d_in[5];
  const float* b_lstm   = (const float*)d_in[6];
  const float* Wx_s     = (const float*)d_in[7];
  const float* Wh_s     = (const float*)d_in[8];
  const float* b_s      = (const float*)d_in[9];
  const float* W_v      = (const float*)d_in[10];
  const float* b_v      = (const float*)d_in[11];
  const float* W_g      = (const float*)d_in[12];
  const float* b_g      = (const float*)d_in[13];
  const float* W_s_att  = (const float*)d_in[14];
  const float* b_sa     = (const float*)d_in[15];
  const float* w_a      = (const float*)d_in[16];
  const float* W_init_h = (const float*)d_in[17];
  const float* b_init_h = (const float*)d_in[18];
  const float* W_init_c = (const float*)d_in[19];
  const float* b_init_c = (const float*)d_in[20];
  const float* W_Lh     = (const float*)d_in[21];
  const float* b_Lh     = (const float*)d_in[22];
  const float* W_Lz     = (const float*)d_in[23];
  const float* b_Lz     = (const float*)d_in[24];
  const float* W_Lo     = (const float*)d_in[25];
  const float* b_Lo     = (const float*)d_in[26];

  float* preds  = (float*)d_out;
  float* alphas = preds + (size_t)B_ * T_ * V_;
  float* betas  = alphas + (size_t)B_ * T_ * L_;

  char* ws = (char*)d_ws;
  size_t off = 0;
  auto alloc = [&](size_t bytes) -> void* {
    void* p = ws + off;
    off = (off + bytes + 255) & ~(size_t)255;
    return p;
  };
  bf16*  enc_p  = (bf16*)alloc((size_t)B_ * L_ * 512 * 2);   // dead after att_v GEMM
  bf16*  enc_r  = (bf16*)alloc((size_t)B_ * L_ * 512 * 2);
  bf16*  attv_b = (bf16*)alloc((size_t)B_ * L_ * 512 * 2);
  bf16*  WT_g   = (bf16*)alloc((size_t)2560 * 1024 * 2);
  bf16*  WT_a   = (bf16*)alloc((size_t)1024 * 1024 * 2);
  bf16*  WT_p   = (bf16*)alloc((size_t)512 * 1024 * 2);
  bf16*  WT_lo  = (bf16*)alloc((size_t)10240 * 512 * 2);
  bf16*  WT_v   = (bf16*)alloc((size_t)512 * 512 * 2);
  bf16*  WT_i   = (bf16*)alloc((size_t)1024 * 512 * 2);
  float* bgx    = (float*)alloc(2560 * 4);
  float* bax    = (float*)alloc(1024 * 4);
  float* bpx    = (float*)alloc(512 * 4);
  float* bix    = (float*)alloc(1024 * 4);
  bf16*  mean_b = (bf16*)alloc(128 * 512 * 2);
  bf16*  A1     = (bf16*)alloc((size_t)(T_ + 1) * 128 * 1024 * 2);
  bf16*  projA  = (bf16*)alloc((size_t)T_ * 128 * 1024 * 2);
  bf16*  projb  = (bf16*)alloc((size_t)T_ * 128 * 512 * 2);
  float* cbuf   = (float*)alloc(128 * 512 * 4);
  unsigned* bar = (unsigned*)alloc(4096);
  if (off > ws_size) return;  // loud validation failure if ws too small

  // Overlay post-scan buffers onto dead enc_p (25,690,112 B):
  //   agsw_all 13,107,200 | Aag 6,553,600 | alphas_raw 2,508,800 | betas_raw 12,800
  float* agsw_all   = (float*)enc_p;
  bf16*  Aag        = (bf16*)((char*)enc_p + 13107200);
  float* alphas_raw = (float*)((char*)enc_p + 19660800);
  float* betas_raw  = (float*)((char*)enc_p + 22169600);

  hipMemsetAsync(bar, 0, 4096, stream);

  // ---- prep ----
  bias_comb<<<dim3(10), dim3(256), 0, stream>>>(b_lstm, b_s, b_g, b_sa, b_Lh, b_Lz,
                                                b_init_h, b_init_c, bgx, bax, bpx, bix);
  auto TP = [&](const float* top, const float* bot, bf16* dst, int ncols, int nrows,
                int ktop, int K) {
    long n8 = (long)nrows * K / 8;
    int blocks = (int)((n8 + 255) / 256);
    if (blocks > 4096) blocks = 4096;
    trans_pack<<<dim3(blocks), dim3(256), 0, stream>>>(top, bot, dst, ncols, n8, ktop, K);
  };
  TP(W_ih, W_hh, WT_g, 2048, 2048, 512, 1024);
  TP(Wx_s, Wh_s, WT_g + (size_t)2048 * 1024, 512, 512, 512, 1024);
  TP(W_Lh, W_Lz, WT_p, 512, 512, 512, 1024);
  TP(W_g, nullptr, WT_a, 512, 512, 512, 1024);
  TP(nullptr, W_s_att, WT_a + (size_t)512 * 1024, 512, 512, 512, 1024);
  TP(W_Lo, nullptr, WT_lo, 10000, 10240, 512, 512);
  TP(W_v, nullptr, WT_v, 512, 512, 512, 512);
  TP(W_init_h, nullptr, WT_i, 512, 512, 512, 512);
  TP(W_init_c, nullptr, WT_i + (size_t)512 * 512, 512, 512, 512, 512);
  conv_pack<<<dim3(4096), dim3(256), 0, stream>>>(enc, enc_p, enc_r,
                                                  (long)B_ * L_ * 512 / 8);
  mean_enc<<<dim3(128, 4), dim3(128), 0, stream>>>(enc, mean_b);
  gather_x<<<dim3(T_ * 128), dim3(64), 0, stream>>>(emb, caps, A1);

  // h0 -> A1[0] h-slot (packed bf16), c0 -> cbuf (f32)
  gemm_pk<1, 1, EPI_INIT><<<dim3(8, 16), dim3(256), 0, stream>>>(
      mean_b, WT_i, bix, (void*)A1, nullptr, cbuf, 128, 1024, 512, 0, 1.f);
  // att_v' = (enc @ W_v + b_v) * ESCL  (bf16 row-major; only e_batch reads it)
  gemm_pk<4, 2, EPI_BF16><<<dim3(392, 4), dim3(256), 0, stream>>>(
      enc_p, WT_v, b_v, attv_b, nullptr, nullptr, B_ * L_, 512, 512, 512, ESCL);

  // ---- persistent 25-step LSTM-only scan (1 barrier/step) ----
  scan26<<<dim3(NBLK), dim3(256), 0, stream>>>(A1, WT_g, bgx, cbuf, Aag, projA, bar);

  // ---- batched attention pipeline ----
  // agsw' = ([h|s]_all @ blockdiag(W_g, W_s_att) + [b_g|b_sa]) * ESCL
  gemm_pk<4, 2, EPI_F32><<<dim3(50, 8), dim3(256), 0, stream>>>(
      Aag, WT_a, bax, agsw_all, nullptr, nullptr, T_ * 128, 1024, 1024, 1024, ESCL);
  // e-scores + softmax for all (b,t)
  e_batch<<<dim3(128, 25), dim3(256), 0, stream>>>(
      attv_b, agsw_all, w_a, clen, alphas, betas, alphas_raw, betas_raw);
  // ctx -> projA ctx-slots (reads enc ONCE, batched over all t)
  ctx_tail<<<dim3(128, 2), dim3(256), 0, stream>>>(alphas_raw, betas_raw, enc_r,
                                                   Aag, projA);
  // proj = x + [h|ctx] @ [W_Lh;W_Lz] + b   (3200 x 512 x 1024, packed out)
  gemm_pk<4, 2, EPI_PROJ><<<dim3(50, 4), dim3(256), 0, stream>>>(
      projA, WT_p, bpx, projb, (const bf16*)A1, nullptr, T_ * 128, 512, 1024, 0, 1.f);
  // preds = proj @ W_Lo + b_Lo  (3200 x 10000 x 512)
  gemm_pk<4, 4, EPI_OUT><<<dim3(50, 40), dim3(256), 0, stream>>>(
      projb, WT_lo, b_Lo, preds, nullptr, nullptr, T_ * 128, V_, 512, 0, 1.f);
}